// Round 1
// baseline (1205.365 us; speedup 1.0000x reference)
//
#include <hip/hip_runtime.h>

typedef unsigned short u16;
typedef u16 ushort8 __attribute__((ext_vector_type(8)));
typedef __bf16 bf16x8 __attribute__((ext_vector_type(8)));
typedef float f32x4 __attribute__((ext_vector_type(4)));

__device__ __forceinline__ u16 f2bf(float f) {
  union { float f; unsigned int u; } v; v.f = f;
  unsigned int r = v.u + 0x7fffu + ((v.u >> 16) & 1u);
  return (u16)(r >> 16);
}
__device__ __forceinline__ float bf2f(u16 u) {
  union { unsigned int u; float f; } v; v.u = ((unsigned int)u) << 16;
  return v.f;
}

// ---------------- tables: DCT D, (1-mask), cos/sin iFFT ----------------
__global__ __launch_bounds__(1024) void k_tables(float* D, float* IM, float* Cc, float* Ss) {
  int t = threadIdx.x;
  int r = t >> 5, c = t & 31;
  const float PI = 3.14159265358979323846f;
  int a = ((2 * c + 1) * r) & 127;              // period 128
  float s = (r == 0) ? 0.17677669529663687f : 0.25f; // sqrt(1/32), sqrt(2/32)
  D[t] = cosf((float)a * (PI / 64.0f)) * s;
  float xy = (float)(r > c ? r : c);
  float m;
  if (xy <= 3.0f)       m = 1.0f - xy * (0.95f / 3.0f);
  else if (xy <= 22.0f) m = 0.01f;
  else                  m = (xy - 22.0f) * 0.03f;
  IM[t] = 1.0f - m;
  int k = (r * c) & 31;                          // period 32
  float ang = (float)k * (PI / 16.0f);
  Cc[t] = cosf(ang);
  Ss[t] = sinf(ang);
}

// ---------------- prep: tok->bf16 (pad 128), W_df->bf16, zero A2, cls copy ----
__global__ __launch_bounds__(256) void k_prep(const float* __restrict__ lt, const int* __restrict__ layerp,
                                              const float* __restrict__ Wdf, const float* __restrict__ feats,
                                              u16* __restrict__ tok_bf, u16* __restrict__ wdf_bf,
                                              u16* __restrict__ A2, float* __restrict__ outp) {
  int L = *layerp;
  for (int i = blockIdx.x * 256 + threadIdx.x; i < 4194304; i += gridDim.x * 256) {
    if (i < 32768) outp[i] = feats[i];                       // cls token row
    if (i < 131072) {
      int m = i >> 10, k = i & 1023;
      float v = (m < 100) ? lt[(size_t)L * 102400 + (size_t)m * 1024 + k] : 0.0f;
      tok_bf[i] = f2bf(v);
    }
    if (i < 1048576) wdf_bf[i] = f2bf(Wdf[i]);
    A2[i] = 0;                                                // attn K-pad zeros
  }
}

// ---------------- S1: cal = vec(D M D^T .* (1-mask)) -> bf16 ----------------
__global__ __launch_bounds__(256) void k_cal(const float* __restrict__ feats, const float* __restrict__ tabD,
                                             const float* __restrict__ tabIM, u16* __restrict__ calb) {
  __shared__ float Ms[1024], T1[1024], Dsh[1024], IMsh[1024];
  int g = blockIdx.x, t = threadIdx.x;
  const float* xrow = feats + 32768 + (size_t)g * 1024;
  for (int i = t; i < 1024; i += 256) { Ms[i] = xrow[i]; Dsh[i] = tabD[i]; IMsh[i] = tabIM[i]; }
  __syncthreads();
  int i0 = t >> 3, l0 = (t & 7) * 4;
  float a0 = 0, a1 = 0, a2 = 0, a3 = 0;
  #pragma unroll 8
  for (int k = 0; k < 32; k++) {
    float d = Dsh[i0 * 32 + k];
    const float* mr = &Ms[k * 32 + l0];
    a0 += d * mr[0]; a1 += d * mr[1]; a2 += d * mr[2]; a3 += d * mr[3];
  }
  T1[i0 * 32 + l0 + 0] = a0; T1[i0 * 32 + l0 + 1] = a1;
  T1[i0 * 32 + l0 + 2] = a2; T1[i0 * 32 + l0 + 3] = a3;
  __syncthreads();
  float b0 = 0, b1 = 0, b2 = 0, b3 = 0;
  #pragma unroll 8
  for (int l = 0; l < 32; l++) {
    float tv = T1[i0 * 32 + l];
    b0 += tv * Dsh[(l0 + 0) * 32 + l];
    b1 += tv * Dsh[(l0 + 1) * 32 + l];
    b2 += tv * Dsh[(l0 + 2) * 32 + l];
    b3 += tv * Dsh[(l0 + 3) * 32 + l];
  }
  size_t base = (size_t)g * 1024 + i0 * 32 + l0;
  int mb = i0 * 32 + l0;
  calb[base + 0] = f2bf(b0 * IMsh[mb + 0]);
  calb[base + 1] = f2bf(b1 * IMsh[mb + 1]);
  calb[base + 2] = f2bf(b2 * IMsh[mb + 2]);
  calb[base + 3] = f2bf(b3 * IMsh[mb + 3]);
}

// ---------------- S4: t2f = tokens[1:] @ W_t2f^T + b, stored transposed (c,m) bf16 ---
__global__ __launch_bounds__(256) void k_t2f(const float* __restrict__ lt, const int* __restrict__ layerp,
                                             const float* __restrict__ W, const float* __restrict__ b,
                                             u16* __restrict__ t2ft) {
  int m = blockIdx.x, t = threadIdx.x;
  if (m >= 99) {
    for (int c = t; c < 1024; c += 256) t2ft[(size_t)c * 128 + m] = 0;
    return;
  }
  __shared__ float tokrow[1024];
  int L = *layerp;
  const float* tr = lt + (size_t)L * 102400 + (size_t)(m + 1) * 1024;
  for (int i = t; i < 1024; i += 256) tokrow[i] = tr[i];
  __syncthreads();
  for (int c = t; c < 1024; c += 256) {
    const float4* w4 = (const float4*)(W + (size_t)c * 1024);
    float acc = 0;
    #pragma unroll 4
    for (int k = 0; k < 256; k++) {
      float4 w = w4[k];
      acc += tokrow[4 * k + 0] * w.x + tokrow[4 * k + 1] * w.y +
             tokrow[4 * k + 2] * w.z + tokrow[4 * k + 3] * w.w;
    }
    t2ft[(size_t)c * 128 + m] = f2bf(acc + b[c]);
  }
}

// ---------------- S2+S3: logits GEMM (M=32768,N=112,K=1024) + fused softmax -> A2 bf16 --
__global__ __launch_bounds__(256) void k_attn(const u16* __restrict__ calb, const u16* __restrict__ tok,
                                              u16* __restrict__ A2) {
  __shared__ __align__(16) u16 As[128 * 40];
  __shared__ __align__(16) u16 Bs[128 * 40];
  int t = threadIdx.x, lane = t & 63, wid = t >> 6;
  int g0 = blockIdx.x * 128;
  int srow = t >> 2, sk = (t & 3) * 8;
  int cl = lane & 15, rg = lane >> 4;
  f32x4 acc[2][7];
  #pragma unroll
  for (int i = 0; i < 2; i++)
    #pragma unroll
    for (int j = 0; j < 7; j++) acc[i][j] = (f32x4){0.f, 0.f, 0.f, 0.f};

  for (int kt = 0; kt < 32; kt++) {
    int k0 = kt * 32;
    ushort8 va0 = *(const ushort8*)(calb + (size_t)(g0 + srow) * 1024 + k0 + sk);
    ushort8 va1 = *(const ushort8*)(calb + (size_t)(g0 + 64 + srow) * 1024 + k0 + sk);
    ushort8 vb0 = *(const ushort8*)(tok + (size_t)srow * 1024 + k0 + sk);
    ushort8 vb1 = *(const ushort8*)(tok + (size_t)(64 + srow) * 1024 + k0 + sk);
    __syncthreads();
    *(ushort8*)(As + srow * 40 + sk) = va0;
    *(ushort8*)(As + (64 + srow) * 40 + sk) = va1;
    *(ushort8*)(Bs + srow * 40 + sk) = vb0;
    *(ushort8*)(Bs + (64 + srow) * 40 + sk) = vb1;
    __syncthreads();
    bf16x8 a0 = *(const bf16x8*)(As + (wid * 32 + cl) * 40 + rg * 8);
    bf16x8 a1 = *(const bf16x8*)(As + (wid * 32 + 16 + cl) * 40 + rg * 8);
    #pragma unroll
    for (int nf = 0; nf < 7; nf++) {
      bf16x8 bfr = *(const bf16x8*)(Bs + (nf * 16 + cl) * 40 + rg * 8);
      acc[0][nf] = __builtin_amdgcn_mfma_f32_16x16x32_bf16(a0, bfr, acc[0][nf], 0, 0, 0);
      acc[1][nf] = __builtin_amdgcn_mfma_f32_16x16x32_bf16(a1, bfr, acc[1][nf], 0, 0, 0);
    }
  }
  // fused softmax over the 100 valid cols; write attn[:,1:100] shifted to A2 cols 0..98
  #pragma unroll
  for (int mf = 0; mf < 2; mf++) {
    #pragma unroll
    for (int r = 0; r < 4; r++) {
      int grow = g0 + wid * 32 + mf * 16 + rg * 4 + r;
      float v[7];
      float mx = -1e30f;
      #pragma unroll
      for (int nf = 0; nf < 7; nf++) {
        int m = nf * 16 + cl;
        v[nf] = acc[mf][nf][r] * 0.03125f;   // * C^-0.5
        if (m < 100) mx = fmaxf(mx, v[nf]);
      }
      #pragma unroll
      for (int d = 1; d < 16; d <<= 1) mx = fmaxf(mx, __shfl_xor(mx, d));
      float s = 0;
      #pragma unroll
      for (int nf = 0; nf < 7; nf++) {
        int m = nf * 16 + cl;
        float e = (m < 100) ? __expf(v[nf] - mx) : 0.0f;
        v[nf] = e; s += e;
      }
      #pragma unroll
      for (int d = 1; d < 16; d <<= 1) s += __shfl_xor(s, d);
      float inv = 1.0f / s;
      #pragma unroll
      for (int nf = 0; nf < 7; nf++) {
        int m = nf * 16 + cl;
        if (m >= 1 && m < 100) A2[(size_t)grow * 128 + (m - 1)] = f2bf(v[nf] * inv);
      }
    }
  }
}

// ---------------- generic 128x128 bf16 MFMA GEMM: out = A@B^T + epilogue ----------------
// ADDCAL: out = acc + cal (bf16, ld 1024). else: out = acc + bias[col].
template <int KITER, bool ADDCAL>
__global__ __launch_bounds__(256) void k_gemm(const u16* __restrict__ A, int lda,
                                              const u16* __restrict__ B, int ldb,
                                              const u16* __restrict__ calb, const float* __restrict__ bias,
                                              u16* __restrict__ outp) {
  __shared__ __align__(16) u16 As[128 * 40];
  __shared__ __align__(16) u16 Bs[128 * 40];
  int t = threadIdx.x, lane = t & 63, wid = t >> 6;
  int bm = blockIdx.x >> 3, bn = blockIdx.x & 7;
  int g0 = bm * 128, c0 = bn * 128;
  int wr = wid >> 1, wc = wid & 1;
  int srow = t >> 2, sk = (t & 3) * 8;
  int cl = lane & 15, rg = lane >> 4;
  f32x4 acc[4][4];
  #pragma unroll
  for (int i = 0; i < 4; i++)
    #pragma unroll
    for (int j = 0; j < 4; j++) acc[i][j] = (f32x4){0.f, 0.f, 0.f, 0.f};

  for (int kt = 0; kt < KITER; kt++) {
    int k0 = kt * 32;
    ushort8 va0 = *(const ushort8*)(A + (size_t)(g0 + srow) * lda + k0 + sk);
    ushort8 va1 = *(const ushort8*)(A + (size_t)(g0 + 64 + srow) * lda + k0 + sk);
    ushort8 vb0 = *(const ushort8*)(B + (size_t)(c0 + srow) * ldb + k0 + sk);
    ushort8 vb1 = *(const ushort8*)(B + (size_t)(c0 + 64 + srow) * ldb + k0 + sk);
    __syncthreads();
    *(ushort8*)(As + srow * 40 + sk) = va0;
    *(ushort8*)(As + (64 + srow) * 40 + sk) = va1;
    *(ushort8*)(Bs + srow * 40 + sk) = vb0;
    *(ushort8*)(Bs + (64 + srow) * 40 + sk) = vb1;
    __syncthreads();
    bf16x8 af[4], bfv[4];
    #pragma unroll
    for (int mf = 0; mf < 4; mf++)
      af[mf] = *(const bf16x8*)(As + (wr * 64 + mf * 16 + cl) * 40 + rg * 8);
    #pragma unroll
    for (int nf = 0; nf < 4; nf++)
      bfv[nf] = *(const bf16x8*)(Bs + (wc * 64 + nf * 16 + cl) * 40 + rg * 8);
    #pragma unroll
    for (int mf = 0; mf < 4; mf++)
      #pragma unroll
      for (int nf = 0; nf < 4; nf++)
        acc[mf][nf] = __builtin_amdgcn_mfma_f32_16x16x32_bf16(af[mf], bfv[nf], acc[mf][nf], 0, 0, 0);
  }
  #pragma unroll
  for (int mf = 0; mf < 4; mf++) {
    #pragma unroll
    for (int nf = 0; nf < 4; nf++) {
      int col = c0 + wc * 64 + nf * 16 + cl;
      #pragma unroll
      for (int r = 0; r < 4; r++) {
        int row = g0 + wr * 64 + mf * 16 + rg * 4 + r;
        float val = acc[mf][nf][r];
        if (ADDCAL) val += bf2f(calb[(size_t)row * 1024 + col]);
        else        val += bias[col];
        outp[(size_t)row * 1024 + col] = f2bf(val);
      }
    }
  }
}

// ---------------- S7: out = clip((C M C^T - S M S^T)/32), final = x + out*scale --------
__global__ __launch_bounds__(256) void k_final(const u16* __restrict__ df2b, const float* __restrict__ feats,
                                               const float* __restrict__ scalep, const float* __restrict__ tabC,
                                               const float* __restrict__ tabS, float* __restrict__ outp) {
  __shared__ float Ms[1024], Uc[1024], Us[1024], Csh[1024], Ssh[1024];
  int g = blockIdx.x, t = threadIdx.x;
  for (int i = t; i < 1024; i += 256) {
    Ms[i] = bf2f(df2b[(size_t)g * 1024 + i]);
    Csh[i] = tabC[i];
    Ssh[i] = tabS[i];
  }
  __syncthreads();
  int k0 = t >> 3, q0 = (t & 7) * 4;
  float c0 = 0, c1 = 0, c2 = 0, c3 = 0, s0 = 0, s1 = 0, s2 = 0, s3 = 0;
  #pragma unroll 8
  for (int l = 0; l < 32; l++) {
    float mv = Ms[k0 * 32 + l];
    c0 += mv * Csh[(q0 + 0) * 32 + l]; s0 += mv * Ssh[(q0 + 0) * 32 + l];
    c1 += mv * Csh[(q0 + 1) * 32 + l]; s1 += mv * Ssh[(q0 + 1) * 32 + l];
    c2 += mv * Csh[(q0 + 2) * 32 + l]; s2 += mv * Ssh[(q0 + 2) * 32 + l];
    c3 += mv * Csh[(q0 + 3) * 32 + l]; s3 += mv * Ssh[(q0 + 3) * 32 + l];
  }
  Uc[k0 * 32 + q0 + 0] = c0; Us[k0 * 32 + q0 + 0] = s0;
  Uc[k0 * 32 + q0 + 1] = c1; Us[k0 * 32 + q0 + 1] = s1;
  Uc[k0 * 32 + q0 + 2] = c2; Us[k0 * 32 + q0 + 2] = s2;
  Uc[k0 * 32 + q0 + 3] = c3; Us[k0 * 32 + q0 + 3] = s3;
  __syncthreads();
  int p = k0;
  float o0 = 0, o1 = 0, o2 = 0, o3 = 0;
  #pragma unroll 8
  for (int k = 0; k < 32; k++) {
    float cp = Csh[p * 32 + k], sp = Ssh[p * 32 + k];
    o0 += cp * Uc[k * 32 + q0 + 0] - sp * Us[k * 32 + q0 + 0];
    o1 += cp * Uc[k * 32 + q0 + 1] - sp * Us[k * 32 + q0 + 1];
    o2 += cp * Uc[k * 32 + q0 + 2] - sp * Us[k * 32 + q0 + 2];
    o3 += cp * Uc[k * 32 + q0 + 3] - sp * Us[k * 32 + q0 + 3];
  }
  float sc = *scalep;
  size_t base = (size_t)g * 1024 + p * 32 + q0;
  const float* xrow = feats + 32768;
  float r0 = fminf(fmaxf(o0 * 0.03125f, 0.f), 255.f);
  float r1 = fminf(fmaxf(o1 * 0.03125f, 0.f), 255.f);
  float r2 = fminf(fmaxf(o2 * 0.03125f, 0.f), 255.f);
  float r3 = fminf(fmaxf(o3 * 0.03125f, 0.f), 255.f);
  outp[32768 + base + 0] = xrow[base + 0] + r0 * sc;
  outp[32768 + base + 1] = xrow[base + 1] + r1 * sc;
  outp[32768 + base + 2] = xrow[base + 2] + r2 * sc;
  outp[32768 + base + 3] = xrow[base + 3] + r3 * sc;
}

extern "C" void kernel_launch(void* const* d_in, const int* in_sizes, int n_in,
                              void* d_out, int out_size, void* d_ws, size_t ws_size,
                              hipStream_t stream) {
  const float* feats  = (const float*)d_in[0];
  const int*   layerp = (const int*)d_in[1];
  const float* lt     = (const float*)d_in[2];
  const float* scalep = (const float*)d_in[3];
  const float* Wt2f   = (const float*)d_in[4];
  const float* bt2f   = (const float*)d_in[5];
  const float* Wdf    = (const float*)d_in[6];
  const float* bdf    = (const float*)d_in[7];
  float* outp = (float*)d_out;

  char* ws = (char*)d_ws;
  float* tabD  = (float*)(ws + 0);
  float* tabIM = (float*)(ws + 4096);
  float* tabC  = (float*)(ws + 8192);
  float* tabS  = (float*)(ws + 12288);
  u16* tok_bf = (u16*)(ws + 65536);        // 128*1024 bf16 (tokens padded)
  u16* t2ft   = (u16*)(ws + 327680);       // 1024*128 bf16 (t2f transposed)
  u16* wdf_bf = (u16*)(ws + 589824);       // 1024*1024 bf16
  u16* A2     = (u16*)(ws + 2686976);      // 32768*128 bf16 (attn[:,1:] K-padded)
  u16* calb   = (u16*)(ws + 11075584);     // 32768*1024 bf16  (also df2 later)
  u16* dfcb   = (u16*)(ws + 78184448);     // 32768*1024 bf16
  u16* df2b   = calb;                      // alias: cal dead after S5

  k_tables<<<1, 1024, 0, stream>>>(tabD, tabIM, tabC, tabS);
  k_prep<<<4096, 256, 0, stream>>>(lt, layerp, Wdf, feats, tok_bf, wdf_bf, A2, outp);
  k_cal<<<32768, 256, 0, stream>>>(feats, tabD, tabIM, calb);
  k_t2f<<<128, 256, 0, stream>>>(lt, layerp, Wt2f, bt2f, t2ft);
  k_attn<<<256, 256, 0, stream>>>(calb, tok_bf, A2);
  k_gemm<4, true><<<2048, 256, 0, stream>>>(A2, 128, t2ft, 128, calb, nullptr, dfcb);
  k_gemm<32, false><<<2048, 256, 0, stream>>>(dfcb, 1024, wdf_bf, 1024, nullptr, bdf, df2b);
  k_final<<<32768, 256, 0, stream>>>(df2b, feats, scalep, tabC, tabS, outp);
}

// Round 2
// 579.280 us; speedup vs baseline: 2.0808x; 2.0808x over previous
//
#include <hip/hip_runtime.h>

typedef unsigned short u16;
typedef u16 ushort8 __attribute__((ext_vector_type(8)));
typedef u16 ushort4v __attribute__((ext_vector_type(4)));
typedef __bf16 bf16x8 __attribute__((ext_vector_type(8)));
typedef float f32x4 __attribute__((ext_vector_type(4)));

__device__ __forceinline__ u16 f2bf(float f) {
  union { float f; unsigned int u; } v; v.f = f;
  unsigned int r = v.u + 0x7fffu + ((v.u >> 16) & 1u);
  return (u16)(r >> 16);
}
__device__ __forceinline__ float bf2f(u16 u) {
  union { unsigned int u; float f; } v; v.u = ((unsigned int)u) << 16;
  return v.f;
}

// ---------------- tables: DCT D, (1-mask), cos/sin iFFT ----------------
__global__ __launch_bounds__(1024) void k_tables(float* D, float* IM, float* Cc, float* Ss) {
  int t = threadIdx.x;
  int r = t >> 5, c = t & 31;
  const float PI = 3.14159265358979323846f;
  int a = ((2 * c + 1) * r) & 127;              // period 128
  float s = (r == 0) ? 0.17677669529663687f : 0.25f; // sqrt(1/32), sqrt(2/32)
  D[t] = cosf((float)a * (PI / 64.0f)) * s;
  float xy = (float)(r > c ? r : c);
  float m;
  if (xy <= 3.0f)       m = 1.0f - xy * (0.95f / 3.0f);
  else if (xy <= 22.0f) m = 0.01f;
  else                  m = (xy - 22.0f) * 0.03f;
  IM[t] = 1.0f - m;
  int k = (r * c) & 31;                          // period 32
  float ang = (float)k * (PI / 16.0f);
  Cc[t] = cosf(ang);
  Ss[t] = sinf(ang);
}

// ---------------- prep: tok->bf16 (pad 128), zero A2, cls copy ----
__global__ __launch_bounds__(256) void k_prep(const float* __restrict__ lt, const int* __restrict__ layerp,
                                              const float* __restrict__ feats,
                                              u16* __restrict__ tok_bf,
                                              u16* __restrict__ A2, float* __restrict__ outp) {
  int L = *layerp;
  for (int i = blockIdx.x * 256 + threadIdx.x; i < 4194304; i += gridDim.x * 256) {
    if (i < 32768) outp[i] = feats[i];                       // cls token row
    if (i < 131072) {
      int m = i >> 10, k = i & 1023;
      float v = (m < 100) ? lt[(size_t)L * 102400 + (size_t)m * 1024 + k] : 0.0f;
      tok_bf[i] = f2bf(v);
    }
    A2[i] = 0;                                                // attn K-pad zeros
  }
}

// ---------------- W_eff = L @ W_df (L = (CxC - SxS)/32), bf16, 4 cols/block ----------
__global__ __launch_bounds__(256) void k_weff(const float* __restrict__ W, const float* __restrict__ tabC,
                                              const float* __restrict__ tabS, u16* __restrict__ weff) {
  __shared__ float In[4 * 1056], Uc[4 * 1056], Us[4 * 1056], Csh[1056], Ssh[1056];
  int t = threadIdx.x;
  int c0 = blockIdx.x * 4;
  for (int i = t; i < 1024; i += 256) {
    int r = i >> 5, c = i & 31;
    Csh[r * 33 + c] = tabC[i];
    Ssh[r * 33 + c] = tabS[i];
  }
  {
    int cc = t & 3, v0 = t >> 2;
    for (int v = v0; v < 1024; v += 64)
      In[cc * 1056 + (v >> 5) * 33 + (v & 31)] = W[(size_t)v * 1024 + c0 + cc];
  }
  __syncthreads();
  int cc = t >> 6, L = t & 63;
  int p = L & 31, h = L >> 5;
  // stage 1: Uc[p][j] = sum_i C[p][i]*M[i][j]
  for (int j = h * 16; j < h * 16 + 16; j++) {
    float ac = 0, as = 0;
    #pragma unroll 8
    for (int i = 0; i < 32; i++) {
      float m = In[cc * 1056 + i * 33 + j];
      ac += Csh[p * 33 + i] * m;
      as += Ssh[p * 33 + i] * m;
    }
    Uc[cc * 1056 + p * 33 + j] = ac;
    Us[cc * 1056 + p * 33 + j] = as;
  }
  __syncthreads();
  // stage 2: out[p][q] = (1/32) sum_j (Uc[p][j]C[q][j] - Us[p][j]S[q][j])
  for (int q = h * 16; q < h * 16 + 16; q++) {
    float acc = 0;
    #pragma unroll 8
    for (int j = 0; j < 32; j++)
      acc += Uc[cc * 1056 + p * 33 + j] * Csh[q * 33 + j] -
             Us[cc * 1056 + p * 33 + j] * Ssh[q * 33 + j];
    weff[(size_t)(p * 32 + q) * 1024 + c0 + cc] = f2bf(acc * 0.03125f);
  }
}

// ---------------- b_eff = L @ b_df, f32 ----------------
__global__ __launch_bounds__(1024) void k_beff(const float* __restrict__ b, const float* __restrict__ tabC,
                                               const float* __restrict__ tabS, float* __restrict__ beff) {
  __shared__ float Bs[1056], Uc[1056], Us[1056], Csh[1056], Ssh[1056];
  int t = threadIdx.x;
  {
    int r = t >> 5, c = t & 31;
    Csh[r * 33 + c] = tabC[t];
    Ssh[r * 33 + c] = tabS[t];
    Bs[r * 33 + c] = b[t];
  }
  __syncthreads();
  int p = t >> 5, j = t & 31;
  float ac = 0, as = 0;
  #pragma unroll 8
  for (int i = 0; i < 32; i++) {
    float m = Bs[i * 33 + j];
    ac += Csh[p * 33 + i] * m;
    as += Ssh[p * 33 + i] * m;
  }
  Uc[p * 33 + j] = ac; Us[p * 33 + j] = as;
  __syncthreads();
  int q = t & 31;
  float acc = 0;
  #pragma unroll 8
  for (int jj = 0; jj < 32; jj++)
    acc += Uc[p * 33 + jj] * Csh[q * 33 + jj] - Us[p * 33 + jj] * Ssh[q * 33 + jj];
  beff[t] = acc * 0.03125f;
}

// ---------------- S1: cal = vec(D M D^T .* (1-mask)) -> bf16 (pad-33 LDS) --------------
__global__ __launch_bounds__(256) void k_cal(const float* __restrict__ feats, const float* __restrict__ tabD,
                                             const float* __restrict__ tabIM, u16* __restrict__ calb) {
  __shared__ float Ms[1056], T1[1056], Dsh[1056], IMsh[1056];
  int g = blockIdx.x, t = threadIdx.x;
  const float* xrow = feats + 32768 + (size_t)g * 1024;
  for (int i = t; i < 1024; i += 256) {
    int r = i >> 5, c = i & 31;
    Ms[r * 33 + c] = xrow[i];
    Dsh[r * 33 + c] = tabD[i];
    IMsh[r * 33 + c] = tabIM[i];
  }
  __syncthreads();
  int i0 = t >> 3, l0 = (t & 7) * 4;
  float a0 = 0, a1 = 0, a2 = 0, a3 = 0;
  #pragma unroll 8
  for (int k = 0; k < 32; k++) {
    float d = Dsh[i0 * 33 + k];
    const float* mr = &Ms[k * 33 + l0];
    a0 += d * mr[0]; a1 += d * mr[1]; a2 += d * mr[2]; a3 += d * mr[3];
  }
  T1[i0 * 33 + l0 + 0] = a0; T1[i0 * 33 + l0 + 1] = a1;
  T1[i0 * 33 + l0 + 2] = a2; T1[i0 * 33 + l0 + 3] = a3;
  __syncthreads();
  float b0 = 0, b1 = 0, b2 = 0, b3 = 0;
  #pragma unroll 8
  for (int l = 0; l < 32; l++) {
    float tv = T1[i0 * 33 + l];
    b0 += tv * Dsh[(l0 + 0) * 33 + l];
    b1 += tv * Dsh[(l0 + 1) * 33 + l];
    b2 += tv * Dsh[(l0 + 2) * 33 + l];
    b3 += tv * Dsh[(l0 + 3) * 33 + l];
  }
  int mb = i0 * 33 + l0;
  ushort4v o;
  o[0] = f2bf(b0 * IMsh[mb + 0]);
  o[1] = f2bf(b1 * IMsh[mb + 1]);
  o[2] = f2bf(b2 * IMsh[mb + 2]);
  o[3] = f2bf(b3 * IMsh[mb + 3]);
  *(ushort4v*)(calb + (size_t)g * 1024 + i0 * 32 + l0) = o;
}

// ---------------- S4: t2f = tokens[1:] @ W_t2f^T + b, stored transposed (c,m) bf16 ---
__global__ __launch_bounds__(256) void k_t2f(const float* __restrict__ lt, const int* __restrict__ layerp,
                                             const float* __restrict__ W, const float* __restrict__ b,
                                             u16* __restrict__ t2ft) {
  int m = blockIdx.x, t = threadIdx.x;
  if (m >= 99) {
    for (int c = t; c < 1024; c += 256) t2ft[(size_t)c * 128 + m] = 0;
    return;
  }
  __shared__ float tokrow[1024];
  int L = *layerp;
  const float* tr = lt + (size_t)L * 102400 + (size_t)(m + 1) * 1024;
  for (int i = t; i < 1024; i += 256) tokrow[i] = tr[i];
  __syncthreads();
  for (int c = t; c < 1024; c += 256) {
    const float4* w4 = (const float4*)(W + (size_t)c * 1024);
    float acc = 0;
    #pragma unroll 4
    for (int k = 0; k < 256; k++) {
      float4 w = w4[k];
      acc += tokrow[4 * k + 0] * w.x + tokrow[4 * k + 1] * w.y +
             tokrow[4 * k + 2] * w.z + tokrow[4 * k + 3] * w.w;
    }
    t2ft[(size_t)c * 128 + m] = f2bf(acc + b[c]);
  }
}

// ---------------- S2+S3: logits GEMM (M=32768,N=112,K=1024) + fused softmax -> A2 bf16 --
__global__ __launch_bounds__(256) void k_attn(const u16* __restrict__ calb, const u16* __restrict__ tok,
                                              u16* __restrict__ A2) {
  __shared__ __align__(16) u16 As[128 * 40];
  __shared__ __align__(16) u16 Bs[128 * 40];
  int t = threadIdx.x, lane = t & 63, wid = t >> 6;
  int g0 = blockIdx.x * 128;
  int srow = t >> 2, sk = (t & 3) * 8;
  int cl = lane & 15, rg = lane >> 4;
  f32x4 acc[2][7];
  #pragma unroll
  for (int i = 0; i < 2; i++)
    #pragma unroll
    for (int j = 0; j < 7; j++) acc[i][j] = (f32x4){0.f, 0.f, 0.f, 0.f};

  for (int kt = 0; kt < 32; kt++) {
    int k0 = kt * 32;
    ushort8 va0 = *(const ushort8*)(calb + (size_t)(g0 + srow) * 1024 + k0 + sk);
    ushort8 va1 = *(const ushort8*)(calb + (size_t)(g0 + 64 + srow) * 1024 + k0 + sk);
    ushort8 vb0 = *(const ushort8*)(tok + (size_t)srow * 1024 + k0 + sk);
    ushort8 vb1 = *(const ushort8*)(tok + (size_t)(64 + srow) * 1024 + k0 + sk);
    __syncthreads();
    *(ushort8*)(As + srow * 40 + sk) = va0;
    *(ushort8*)(As + (64 + srow) * 40 + sk) = va1;
    *(ushort8*)(Bs + srow * 40 + sk) = vb0;
    *(ushort8*)(Bs + (64 + srow) * 40 + sk) = vb1;
    __syncthreads();
    bf16x8 a0 = *(const bf16x8*)(As + (wid * 32 + cl) * 40 + rg * 8);
    bf16x8 a1 = *(const bf16x8*)(As + (wid * 32 + 16 + cl) * 40 + rg * 8);
    #pragma unroll
    for (int nf = 0; nf < 7; nf++) {
      bf16x8 bfr = *(const bf16x8*)(Bs + (nf * 16 + cl) * 40 + rg * 8);
      acc[0][nf] = __builtin_amdgcn_mfma_f32_16x16x32_bf16(a0, bfr, acc[0][nf], 0, 0, 0);
      acc[1][nf] = __builtin_amdgcn_mfma_f32_16x16x32_bf16(a1, bfr, acc[1][nf], 0, 0, 0);
    }
  }
  #pragma unroll
  for (int mf = 0; mf < 2; mf++) {
    #pragma unroll
    for (int r = 0; r < 4; r++) {
      int grow = g0 + wid * 32 + mf * 16 + rg * 4 + r;
      float v[7];
      float mx = -1e30f;
      #pragma unroll
      for (int nf = 0; nf < 7; nf++) {
        int m = nf * 16 + cl;
        v[nf] = acc[mf][nf][r] * 0.03125f;   // * C^-0.5
        if (m < 100) mx = fmaxf(mx, v[nf]);
      }
      #pragma unroll
      for (int d = 1; d < 16; d <<= 1) mx = fmaxf(mx, __shfl_xor(mx, d));
      float s = 0;
      #pragma unroll
      for (int nf = 0; nf < 7; nf++) {
        int m = nf * 16 + cl;
        float e = (m < 100) ? __expf(v[nf] - mx) : 0.0f;
        v[nf] = e; s += e;
      }
      #pragma unroll
      for (int d = 1; d < 16; d <<= 1) s += __shfl_xor(s, d);
      float inv = 1.0f / s;
      #pragma unroll
      for (int nf = 0; nf < 7; nf++) {
        int m = nf * 16 + cl;
        if (m >= 1 && m < 100) A2[(size_t)grow * 128 + (m - 1)] = f2bf(v[nf] * inv);
      }
    }
  }
}

// ---------------- generic 128x128 bf16 MFMA GEMM: out = A@B^T + epilogue ----------------
// MODE 0: out_bf16 = acc + cal.  MODE 1: r=clip(acc+bias,0,255); out_f32 = x + r*scale.
template <int KITER, int MODE>
__global__ __launch_bounds__(256) void k_gemm(const u16* __restrict__ A, int lda,
                                              const u16* __restrict__ B, int ldb,
                                              const u16* __restrict__ calb, const float* __restrict__ bias,
                                              const float* __restrict__ feats, const float* __restrict__ scalep,
                                              u16* __restrict__ outb, float* __restrict__ outf) {
  __shared__ __align__(16) u16 As[128 * 40];
  __shared__ __align__(16) u16 Bs[128 * 40];
  int t = threadIdx.x, lane = t & 63, wid = t >> 6;
  int bm = blockIdx.x >> 3, bn = blockIdx.x & 7;
  int g0 = bm * 128, c0 = bn * 128;
  int wr = wid >> 1, wc = wid & 1;
  int srow = t >> 2, sk = (t & 3) * 8;
  int cl = lane & 15, rg = lane >> 4;
  f32x4 acc[4][4];
  #pragma unroll
  for (int i = 0; i < 4; i++)
    #pragma unroll
    for (int j = 0; j < 4; j++) acc[i][j] = (f32x4){0.f, 0.f, 0.f, 0.f};

  for (int kt = 0; kt < KITER; kt++) {
    int k0 = kt * 32;
    ushort8 va0 = *(const ushort8*)(A + (size_t)(g0 + srow) * lda + k0 + sk);
    ushort8 va1 = *(const ushort8*)(A + (size_t)(g0 + 64 + srow) * lda + k0 + sk);
    ushort8 vb0 = *(const ushort8*)(B + (size_t)(c0 + srow) * ldb + k0 + sk);
    ushort8 vb1 = *(const ushort8*)(B + (size_t)(c0 + 64 + srow) * ldb + k0 + sk);
    __syncthreads();
    *(ushort8*)(As + srow * 40 + sk) = va0;
    *(ushort8*)(As + (64 + srow) * 40 + sk) = va1;
    *(ushort8*)(Bs + srow * 40 + sk) = vb0;
    *(ushort8*)(Bs + (64 + srow) * 40 + sk) = vb1;
    __syncthreads();
    bf16x8 af[4], bfv[4];
    #pragma unroll
    for (int mf = 0; mf < 4; mf++)
      af[mf] = *(const bf16x8*)(As + (wr * 64 + mf * 16 + cl) * 40 + rg * 8);
    #pragma unroll
    for (int nf = 0; nf < 4; nf++)
      bfv[nf] = *(const bf16x8*)(Bs + (wc * 64 + nf * 16 + cl) * 40 + rg * 8);
    #pragma unroll
    for (int mf = 0; mf < 4; mf++)
      #pragma unroll
      for (int nf = 0; nf < 4; nf++)
        acc[mf][nf] = __builtin_amdgcn_mfma_f32_16x16x32_bf16(af[mf], bfv[nf], acc[mf][nf], 0, 0, 0);
  }
  float sc = (MODE == 1) ? *scalep : 0.0f;
  #pragma unroll
  for (int mf = 0; mf < 4; mf++) {
    #pragma unroll
    for (int nf = 0; nf < 4; nf++) {
      int col = c0 + wc * 64 + nf * 16 + cl;
      #pragma unroll
      for (int r = 0; r < 4; r++) {
        int row = g0 + wr * 64 + mf * 16 + rg * 4 + r;
        size_t idx = (size_t)row * 1024 + col;
        float val = acc[mf][nf][r];
        if (MODE == 0) {
          val += bf2f(calb[idx]);
          outb[idx] = f2bf(val);
        } else {
          val += bias[col];
          float rr = fminf(fmaxf(val, 0.f), 255.f);
          outf[32768 + idx] = feats[32768 + idx] + rr * sc;
        }
      }
    }
  }
}

extern "C" void kernel_launch(void* const* d_in, const int* in_sizes, int n_in,
                              void* d_out, int out_size, void* d_ws, size_t ws_size,
                              hipStream_t stream) {
  const float* feats  = (const float*)d_in[0];
  const int*   layerp = (const int*)d_in[1];
  const float* lt     = (const float*)d_in[2];
  const float* scalep = (const float*)d_in[3];
  const float* Wt2f   = (const float*)d_in[4];
  const float* bt2f   = (const float*)d_in[5];
  const float* Wdf    = (const float*)d_in[6];
  const float* bdf    = (const float*)d_in[7];
  float* outp = (float*)d_out;

  char* ws = (char*)d_ws;
  float* tabD  = (float*)(ws + 0);
  float* tabIM = (float*)(ws + 4096);
  float* tabC  = (float*)(ws + 8192);
  float* tabS  = (float*)(ws + 12288);
  float* beff  = (float*)(ws + 16384);     // 1024 f32
  u16* tok_bf = (u16*)(ws + 65536);        // 128*1024 bf16 (tokens padded)
  u16* t2ft   = (u16*)(ws + 327680);       // 1024*128 bf16 (t2f transposed)
  u16* weff   = (u16*)(ws + 589824);       // 1024*1024 bf16 (L @ W_df)
  u16* A2     = (u16*)(ws + 2686976);      // 32768*128 bf16 (attn[:,1:] K-padded)
  u16* calb   = (u16*)(ws + 11075584);     // 32768*1024 bf16
  u16* dfcb   = (u16*)(ws + 78184448);     // 32768*1024 bf16

  k_tables<<<1, 1024, 0, stream>>>(tabD, tabIM, tabC, tabS);
  k_prep<<<4096, 256, 0, stream>>>(lt, layerp, feats, tok_bf, A2, outp);
  k_weff<<<256, 256, 0, stream>>>(Wdf, tabC, tabS, weff);
  k_beff<<<1, 1024, 0, stream>>>(bdf, tabC, tabS, beff);
  k_cal<<<32768, 256, 0, stream>>>(feats, tabD, tabIM, calb);
  k_t2f<<<128, 256, 0, stream>>>(lt, layerp, Wt2f, bt2f, t2ft);
  k_attn<<<256, 256, 0, stream>>>(calb, tok_bf, A2);
  k_gemm<4, 0><<<2048, 256, 0, stream>>>(A2, 128, t2ft, 128, calb, nullptr, nullptr, nullptr, dfcb, nullptr);
  k_gemm<32, 1><<<2048, 256, 0, stream>>>(dfcb, 1024, weff, 1024, nullptr, beff, feats, scalep, nullptr, outp);
}

// Round 3
// 468.342 us; speedup vs baseline: 2.5737x; 1.2369x over previous
//
#include <hip/hip_runtime.h>

typedef unsigned short u16;
typedef u16 ushort8 __attribute__((ext_vector_type(8)));
typedef u16 ushort4v __attribute__((ext_vector_type(4)));
typedef __bf16 bf16x8 __attribute__((ext_vector_type(8)));
typedef float f32x4 __attribute__((ext_vector_type(4)));

__device__ __forceinline__ u16 f2bf(float f) {
  union { float f; unsigned int u; } v; v.f = f;
  unsigned int r = v.u + 0x7fffu + ((v.u >> 16) & 1u);
  return (u16)(r >> 16);
}
__device__ __forceinline__ float bf2f(u16 u) {
  union { unsigned int u; float f; } v; v.u = ((unsigned int)u) << 16;
  return v.f;
}

// async global->LDS, 16B per lane; LDS dest = wave-uniform base + lane*16
__device__ __forceinline__ void gload16(const u16* g, u16* l) {
  __builtin_amdgcn_global_load_lds((const __attribute__((address_space(1))) void*)g,
                                   (__attribute__((address_space(3))) void*)l, 16, 0, 0);
}

// stage a 128x32 bf16 tile (rows row0.., K offset k0, leading dim ld) into linear LDS [128][32]
__device__ __forceinline__ void stage_tile(const u16* __restrict__ G, int ld, int row0, int k0,
                                           u16* lds, int wid, int lane) {
  int seg = wid * 32;  // this wave's 32 rows
  const u16* gp = G + (size_t)(row0 + seg + (lane >> 2)) * ld + k0 + (lane & 3) * 8;
  gload16(gp, lds + seg * 32);
  gload16(gp + (size_t)16 * ld, lds + (seg + 16) * 32);
}

// ---------------- tables: DCT D, (1-mask), cos/sin iFFT ----------------
__global__ __launch_bounds__(1024) void k_tables(float* D, float* IM, float* Cc, float* Ss) {
  int t = threadIdx.x;
  int r = t >> 5, c = t & 31;
  const float PI = 3.14159265358979323846f;
  int a = ((2 * c + 1) * r) & 127;
  float s = (r == 0) ? 0.17677669529663687f : 0.25f;
  D[t] = cosf((float)a * (PI / 64.0f)) * s;
  float xy = (float)(r > c ? r : c);
  float m;
  if (xy <= 3.0f)       m = 1.0f - xy * (0.95f / 3.0f);
  else if (xy <= 22.0f) m = 0.01f;
  else                  m = (xy - 22.0f) * 0.03f;
  IM[t] = 1.0f - m;
  int k = (r * c) & 31;
  float ang = (float)k * (PI / 16.0f);
  Cc[t] = cosf(ang);
  Ss[t] = sinf(ang);
}

// ---------------- prep: x->bf16, cls copy, zero A2 + Gt ----------------
__global__ __launch_bounds__(256) void k_prep(const float* __restrict__ feats,
                                              u16* __restrict__ xb, u16* __restrict__ A2,
                                              u16* __restrict__ Gt, float* __restrict__ outp) {
  int tid = blockIdx.x * 256 + threadIdx.x;           // 524288 threads
  const float4* in4 = (const float4*)(feats + 32768);
  ushort4v* xb4 = (ushort4v*)xb;
  for (int j = tid; j < 8388608; j += 524288) {
    float4 v = in4[j];
    ushort4v o;
    o[0] = f2bf(v.x); o[1] = f2bf(v.y); o[2] = f2bf(v.z); o[3] = f2bf(v.w);
    xb4[j] = o;
  }
  if (tid < 32768) outp[tid] = feats[tid];
  ((ushort8*)A2)[tid] = (ushort8){0,0,0,0,0,0,0,0};    // 524288*8 = 4194304
  if (tid < 16384) ((ushort8*)Gt)[tid] = (ushort8){0,0,0,0,0,0,0,0};
}

// ---------------- W_eff = L @ W_df (L = (CxC - SxS)/32): f32 + bf16 ----------
__global__ __launch_bounds__(256) void k_weff(const float* __restrict__ W, const float* __restrict__ tabC,
                                              const float* __restrict__ tabS,
                                              float* __restrict__ weff_f, u16* __restrict__ weff_bf) {
  __shared__ float In[4 * 1056], Uc[4 * 1056], Us[4 * 1056], Csh[1056], Ssh[1056];
  int t = threadIdx.x;
  int c0 = blockIdx.x * 4;
  for (int i = t; i < 1024; i += 256) {
    int r = i >> 5, c = i & 31;
    Csh[r * 33 + c] = tabC[i];
    Ssh[r * 33 + c] = tabS[i];
  }
  {
    int cc = t & 3, v0 = t >> 2;
    for (int v = v0; v < 1024; v += 64)
      In[cc * 1056 + (v >> 5) * 33 + (v & 31)] = W[(size_t)v * 1024 + c0 + cc];
  }
  __syncthreads();
  int cc = t >> 6, L = t & 63;
  int p = L & 31, h = L >> 5;
  for (int j = h * 16; j < h * 16 + 16; j++) {
    float ac = 0, as = 0;
    #pragma unroll 8
    for (int i = 0; i < 32; i++) {
      float m = In[cc * 1056 + i * 33 + j];
      ac += Csh[p * 33 + i] * m;
      as += Ssh[p * 33 + i] * m;
    }
    Uc[cc * 1056 + p * 33 + j] = ac;
    Us[cc * 1056 + p * 33 + j] = as;
  }
  __syncthreads();
  for (int q = h * 16; q < h * 16 + 16; q++) {
    float acc = 0;
    #pragma unroll 8
    for (int j = 0; j < 32; j++)
      acc += Uc[cc * 1056 + p * 33 + j] * Csh[q * 33 + j] -
             Us[cc * 1056 + p * 33 + j] * Ssh[q * 33 + j];
    float val = acc * 0.03125f;
    size_t idx = (size_t)(p * 32 + q) * 1024 + c0 + cc;
    weff_f[idx] = val;
    weff_bf[idx] = f2bf(val);
  }
}

// ---------------- b_eff = L @ b_df ----------------
__global__ __launch_bounds__(1024) void k_beff(const float* __restrict__ b, const float* __restrict__ tabC,
                                               const float* __restrict__ tabS, float* __restrict__ beff) {
  __shared__ float Bs[1056], Uc[1056], Us[1056], Csh[1056], Ssh[1056];
  int t = threadIdx.x;
  {
    int r = t >> 5, c = t & 31;
    Csh[r * 33 + c] = tabC[t];
    Ssh[r * 33 + c] = tabS[t];
    Bs[r * 33 + c] = b[t];
  }
  __syncthreads();
  int p = t >> 5, j = t & 31;
  float ac = 0, as = 0;
  #pragma unroll 8
  for (int i = 0; i < 32; i++) {
    float m = Bs[i * 33 + j];
    ac += Csh[p * 33 + i] * m;
    as += Ssh[p * 33 + i] * m;
  }
  Uc[p * 33 + j] = ac; Us[p * 33 + j] = as;
  __syncthreads();
  int q = t & 31;
  float acc = 0;
  #pragma unroll 8
  for (int jj = 0; jj < 32; jj++)
    acc += Uc[p * 33 + jj] * Csh[q * 33 + jj] - Us[p * 33 + jj] * Ssh[q * 33 + jj];
  beff[t] = acc * 0.03125f;
}

// ---------------- masked-DCT adjoint per row: dst[p] = vec(D^T(im.*mat(src_p))D) ----------
// mode=1: src += (*layerp)*102400. rows >= nrows are zeroed.
__global__ __launch_bounds__(256) void k_mdct(const float* __restrict__ src, const int* __restrict__ layerp,
                                              int mode, int nrows, const float* __restrict__ tabD,
                                              const float* __restrict__ tabIM, u16* __restrict__ dst) {
  int p = blockIdx.x, t = threadIdx.x;
  if (p >= nrows) {
    ((ushort4v*)dst)[p * 256 + t] = (ushort4v){0,0,0,0};
    return;
  }
  __shared__ float Ms[1056], T1[1056], Dsh[1056];
  const float* row = src + (mode ? (size_t)(*layerp) * 102400 : (size_t)0) + (size_t)p * 1024;
  for (int i = t; i < 1024; i += 256) {
    int r = i >> 5, c = i & 31;
    Ms[r * 33 + c] = row[i] * tabIM[i];   // im .* M
    Dsh[r * 33 + c] = tabD[i];
  }
  __syncthreads();
  int k = t >> 3, l0 = (t & 7) * 4;
  // stage 1: U[k][j] = sum_i D[i][k] * Ms[i][j]
  float a0 = 0, a1 = 0, a2 = 0, a3 = 0;
  #pragma unroll 8
  for (int i = 0; i < 32; i++) {
    float d = Dsh[i * 33 + k];
    const float* mr = &Ms[i * 33 + l0];
    a0 += d * mr[0]; a1 += d * mr[1]; a2 += d * mr[2]; a3 += d * mr[3];
  }
  T1[k * 33 + l0 + 0] = a0; T1[k * 33 + l0 + 1] = a1;
  T1[k * 33 + l0 + 2] = a2; T1[k * 33 + l0 + 3] = a3;
  __syncthreads();
  // stage 2: out[k][l] = sum_j U[k][j] * D[j][l]
  float b0 = 0, b1 = 0, b2 = 0, b3 = 0;
  #pragma unroll 8
  for (int j = 0; j < 32; j++) {
    float u = T1[k * 33 + j];
    b0 += u * Dsh[j * 33 + l0 + 0];
    b1 += u * Dsh[j * 33 + l0 + 1];
    b2 += u * Dsh[j * 33 + l0 + 2];
    b3 += u * Dsh[j * 33 + l0 + 3];
  }
  ushort4v o;
  o[0] = f2bf(b0); o[1] = f2bf(b1); o[2] = f2bf(b2); o[3] = f2bf(b3);
  *(ushort4v*)(dst + (size_t)p * 1024 + k * 32 + l0) = o;
}

// ---------------- t2f = tokens[1:] @ W_t2f^T + b, row-major bf16 (128x1024, pad zero) ---
__global__ __launch_bounds__(256) void k_t2f(const float* __restrict__ lt, const int* __restrict__ layerp,
                                             const float* __restrict__ W, const float* __restrict__ b,
                                             u16* __restrict__ t2f) {
  int m = blockIdx.x, t = threadIdx.x;
  if (m >= 99) {
    for (int c = t; c < 1024; c += 256) t2f[(size_t)m * 1024 + c] = 0;
    return;
  }
  __shared__ float tokrow[1024];
  int L = *layerp;
  const float* tr = lt + (size_t)L * 102400 + (size_t)(m + 1) * 1024;
  for (int i = t; i < 1024; i += 256) tokrow[i] = tr[i];
  __syncthreads();
  for (int c = t; c < 1024; c += 256) {
    const float4* w4 = (const float4*)(W + (size_t)c * 1024);
    float acc = 0;
    #pragma unroll 4
    for (int k = 0; k < 256; k++) {
      float4 w = w4[k];
      acc += tokrow[4 * k + 0] * w.x + tokrow[4 * k + 1] * w.y +
             tokrow[4 * k + 2] * w.z + tokrow[4 * k + 3] * w.w;
    }
    t2f[(size_t)m * 1024 + c] = f2bf(acc + b[c]);
  }
}

// ---------------- narrow GEMM: out(Mx112) = A(Mx1024) @ B(128x1024)^T ----------------
// SM=true: fused softmax over cols 0..99, write shifted cols 1..99 -> out[g*128 + m-1]
// SM=false: write raw bf16 -> out[row*128 + col]
template <bool SM>
__global__ __launch_bounds__(256) void k_ngemm(const u16* __restrict__ A, const u16* __restrict__ B,
                                               u16* __restrict__ out) {
  __shared__ __align__(16) u16 As[128 * 32];
  __shared__ __align__(16) u16 Bs[128 * 32];
  int t = threadIdx.x, lane = t & 63, wid = t >> 6;
  int g0 = blockIdx.x * 128;
  int cl = lane & 15, rg = lane >> 4;
  f32x4 acc[2][7];
  #pragma unroll
  for (int i = 0; i < 2; i++)
    #pragma unroll
    for (int j = 0; j < 7; j++) acc[i][j] = (f32x4){0.f, 0.f, 0.f, 0.f};

  for (int kt = 0; kt < 32; kt++) {
    int k0 = kt * 32;
    stage_tile(A, 1024, g0, k0, As, wid, lane);
    stage_tile(B, 1024, 0, k0, Bs, wid, lane);
    __syncthreads();
    bf16x8 a0 = *(const bf16x8*)(As + (wid * 32 + cl) * 32 + rg * 8);
    bf16x8 a1 = *(const bf16x8*)(As + (wid * 32 + 16 + cl) * 32 + rg * 8);
    #pragma unroll
    for (int nf = 0; nf < 7; nf++) {
      bf16x8 bv = *(const bf16x8*)(Bs + (nf * 16 + cl) * 32 + rg * 8);
      acc[0][nf] = __builtin_amdgcn_mfma_f32_16x16x32_bf16(a0, bv, acc[0][nf], 0, 0, 0);
      acc[1][nf] = __builtin_amdgcn_mfma_f32_16x16x32_bf16(a1, bv, acc[1][nf], 0, 0, 0);
    }
    __syncthreads();
  }
  if (SM) {
    #pragma unroll
    for (int mf = 0; mf < 2; mf++) {
      #pragma unroll
      for (int r = 0; r < 4; r++) {
        int grow = g0 + wid * 32 + mf * 16 + rg * 4 + r;
        float v[7];
        float mx = -1e30f;
        #pragma unroll
        for (int nf = 0; nf < 7; nf++) {
          int m = nf * 16 + cl;
          v[nf] = acc[mf][nf][r] * 0.03125f;
          if (m < 100) mx = fmaxf(mx, v[nf]);
        }
        #pragma unroll
        for (int d = 1; d < 16; d <<= 1) mx = fmaxf(mx, __shfl_xor(mx, d));
        float s = 0;
        #pragma unroll
        for (int nf = 0; nf < 7; nf++) {
          int m = nf * 16 + cl;
          float e = (m < 100) ? __expf(v[nf] - mx) : 0.0f;
          v[nf] = e; s += e;
        }
        #pragma unroll
        for (int d = 1; d < 16; d <<= 1) s += __shfl_xor(s, d);
        float inv = 1.0f / s;
        #pragma unroll
        for (int nf = 0; nf < 7; nf++) {
          int m = nf * 16 + cl;
          if (m >= 1 && m < 100) out[(size_t)grow * 128 + (m - 1)] = f2bf(v[nf] * inv);
        }
      }
    }
  } else {
    #pragma unroll
    for (int mf = 0; mf < 2; mf++) {
      #pragma unroll
      for (int nf = 0; nf < 7; nf++) {
        int col = nf * 16 + cl;
        #pragma unroll
        for (int r = 0; r < 4; r++) {
          int row = g0 + wid * 32 + mf * 16 + rg * 4 + r;
          out[(size_t)row * 128 + col] = f2bf(acc[mf][nf][r]);
        }
      }
    }
  }
}

// ---------------- main fused GEMM: out = x + clip(xb@W2^T + A2@Gt^T + beff, 0,255)*scale --
__global__ __launch_bounds__(256) void k_main(const u16* __restrict__ xb, const u16* __restrict__ w2,
                                              const u16* __restrict__ a2, const u16* __restrict__ gt,
                                              const float* __restrict__ beff, const float* __restrict__ feats,
                                              const float* __restrict__ scalep, float* __restrict__ outf) {
  __shared__ __align__(16) u16 As[128 * 32];
  __shared__ __align__(16) u16 Bs[128 * 32];
  int t = threadIdx.x, lane = t & 63, wid = t >> 6;
  // bijective XCD-aware swizzle: same bm stays on one XCD; groups of 4 bm x 8 bn share L2
  int bid = blockIdx.x;
  int xcd = bid & 7, local = bid >> 3;
  int super = local >> 5, within = local & 31;
  int bm = xcd * 32 + super * 4 + (within & 3);
  int bn = within >> 2;
  int g0 = bm * 128, c0 = bn * 128;
  int wr = wid >> 1, wc = wid & 1;
  int cl = lane & 15, rg = lane >> 4;
  f32x4 acc[4][4];
  #pragma unroll
  for (int i = 0; i < 4; i++)
    #pragma unroll
    for (int j = 0; j < 4; j++) acc[i][j] = (f32x4){0.f, 0.f, 0.f, 0.f};

  #pragma unroll 1
  for (int kt = 0; kt < 32; kt++) {
    stage_tile(xb, 1024, g0, kt * 32, As, wid, lane);
    stage_tile(w2, 1024, c0, kt * 32, Bs, wid, lane);
    __syncthreads();
    bf16x8 af[4], bv[4];
    #pragma unroll
    for (int mf = 0; mf < 4; mf++)
      af[mf] = *(const bf16x8*)(As + (wr * 64 + mf * 16 + cl) * 32 + rg * 8);
    #pragma unroll
    for (int nf = 0; nf < 4; nf++)
      bv[nf] = *(const bf16x8*)(Bs + (wc * 64 + nf * 16 + cl) * 32 + rg * 8);
    #pragma unroll
    for (int mf = 0; mf < 4; mf++)
      #pragma unroll
      for (int nf = 0; nf < 4; nf++)
        acc[mf][nf] = __builtin_amdgcn_mfma_f32_16x16x32_bf16(af[mf], bv[nf], acc[mf][nf], 0, 0, 0);
    __syncthreads();
  }
  #pragma unroll 1
  for (int kt = 0; kt < 4; kt++) {
    stage_tile(a2, 128, g0, kt * 32, As, wid, lane);
    stage_tile(gt, 128, c0, kt * 32, Bs, wid, lane);
    __syncthreads();
    bf16x8 af[4], bv[4];
    #pragma unroll
    for (int mf = 0; mf < 4; mf++)
      af[mf] = *(const bf16x8*)(As + (wr * 64 + mf * 16 + cl) * 32 + rg * 8);
    #pragma unroll
    for (int nf = 0; nf < 4; nf++)
      bv[nf] = *(const bf16x8*)(Bs + (wc * 64 + nf * 16 + cl) * 32 + rg * 8);
    #pragma unroll
    for (int mf = 0; mf < 4; mf++)
      #pragma unroll
      for (int nf = 0; nf < 4; nf++)
        acc[mf][nf] = __builtin_amdgcn_mfma_f32_16x16x32_bf16(af[mf], bv[nf], acc[mf][nf], 0, 0, 0);
    __syncthreads();
  }
  float sc = *scalep;
  #pragma unroll
  for (int mf = 0; mf < 4; mf++) {
    #pragma unroll
    for (int nf = 0; nf < 4; nf++) {
      int col = c0 + wc * 64 + nf * 16 + cl;
      #pragma unroll
      for (int r = 0; r < 4; r++) {
        int row = g0 + wr * 64 + mf * 16 + rg * 4 + r;
        size_t idx = (size_t)row * 1024 + col;
        float val = acc[mf][nf][r] + beff[col];
        float rr = fminf(fmaxf(val, 0.f), 255.f);
        outf[32768 + idx] = feats[32768 + idx] + rr * sc;
      }
    }
  }
}

extern "C" void kernel_launch(void* const* d_in, const int* in_sizes, int n_in,
                              void* d_out, int out_size, void* d_ws, size_t ws_size,
                              hipStream_t stream) {
  const float* feats  = (const float*)d_in[0];
  const int*   layerp = (const int*)d_in[1];
  const float* lt     = (const float*)d_in[2];
  const float* scalep = (const float*)d_in[3];
  const float* Wt2f   = (const float*)d_in[4];
  const float* bt2f   = (const float*)d_in[5];
  const float* Wdf    = (const float*)d_in[6];
  const float* bdf    = (const float*)d_in[7];
  float* outp = (float*)d_out;

  char* ws = (char*)d_ws;
  float* tabD   = (float*)(ws + 0);
  float* tabIM  = (float*)(ws + 4096);
  float* tabC   = (float*)(ws + 8192);
  float* tabS   = (float*)(ws + 12288);
  float* beff   = (float*)(ws + 16384);      // 4KB
  float* weff_f = (float*)(ws + 65536);      // 4MB f32
  u16* weff_bf = (u16*)(ws + 4259840);       // 2MB
  u16* w2      = (u16*)(ws + 6356992);       // 2MB
  u16* tok2    = (u16*)(ws + 8454144);       // 256KB (128x1024)
  u16* t2f     = (u16*)(ws + 8716288);       // 256KB (128x1024)
  u16* Gt      = (u16*)(ws + 8978432);       // 256KB (1024x128)
  u16* A2      = (u16*)(ws + 9240576);       // 8MB (32768x128)
  u16* xb      = (u16*)(ws + 17629184);      // 64MB (32768x1024)

  k_tables<<<1, 1024, 0, stream>>>(tabD, tabIM, tabC, tabS);
  k_prep<<<2048, 256, 0, stream>>>(feats, xb, A2, Gt, outp);
  k_weff<<<256, 256, 0, stream>>>(Wdf, tabC, tabS, weff_f, weff_bf);
  k_beff<<<1, 1024, 0, stream>>>(bdf, tabC, tabS, beff);
  k_mdct<<<1024, 256, 0, stream>>>(weff_f, layerp, 0, 1024, tabD, tabIM, w2);
  k_mdct<<<128, 256, 0, stream>>>(lt, layerp, 1, 100, tabD, tabIM, tok2);
  k_t2f<<<128, 256, 0, stream>>>(lt, layerp, Wt2f, bt2f, t2f);
  k_ngemm<false><<<8, 256, 0, stream>>>(weff_bf, t2f, Gt);
  k_ngemm<true><<<256, 256, 0, stream>>>(xb, tok2, A2);
  k_main<<<2048, 256, 0, stream>>>(xb, w2, A2, Gt, beff, feats, scalep, outp);
}

// Round 4
// 254.258 us; speedup vs baseline: 4.7407x; 1.8420x over previous
//
#include <hip/hip_runtime.h>

typedef unsigned short u16;
typedef u16 ushort8 __attribute__((ext_vector_type(8)));
typedef u16 ushort4v __attribute__((ext_vector_type(4)));
typedef __bf16 bf16x8 __attribute__((ext_vector_type(8)));
typedef float f32x4 __attribute__((ext_vector_type(4)));

#define PI_F 3.14159265358979323846f

__device__ __forceinline__ u16 f2bf(float f) {
  union { float f; unsigned int u; } v; v.f = f;
  unsigned int r = v.u + 0x7fffu + ((v.u >> 16) & 1u);
  return (u16)(r >> 16);
}
__device__ __forceinline__ float bf2f(u16 u) {
  union { unsigned int u; float f; } v; v.u = ((unsigned int)u) << 16;
  return v.f;
}

// async global->LDS, 16B per lane; LDS dest = wave-uniform base + lane*16
__device__ __forceinline__ void gload16(const u16* g, u16* l) {
  __builtin_amdgcn_global_load_lds((const __attribute__((address_space(1))) void*)g,
                                   (__attribute__((address_space(3))) void*)l, 16, 0, 0);
}

// stage a 128x32 bf16 tile into linear LDS [128][32]
__device__ __forceinline__ void stage_tile(const u16* __restrict__ G, int ld, int row0, int k0,
                                           u16* lds, int wid, int lane) {
  int seg = wid * 32;
  const u16* gp = G + (size_t)(row0 + seg + (lane >> 2)) * ld + k0 + (lane & 3) * 8;
  gload16(gp, lds + seg * 32);
  gload16(gp + (size_t)16 * ld, lds + (seg + 16) * 32);
}

// local 32x32 tables
__device__ __forceinline__ float im_val(int r, int c) {
  float xy = (float)(r > c ? r : c);
  float m = (xy <= 3.0f) ? (1.0f - xy * (0.95f / 3.0f))
           : ((xy <= 22.0f) ? 0.01f : ((xy - 22.0f) * 0.03f));
  return 1.0f - m;
}
__device__ __forceinline__ float dct_val(int r, int c) {
  int a = ((2 * c + 1) * r) & 127;
  float s = (r == 0) ? 0.17677669529663687f : 0.25f;
  return cosf((float)a * (PI_F / 64.0f)) * s;
}

// ---------------- prep: xb, wt_bf, tok_bf, zero A2, cls copy ----------------
__global__ __launch_bounds__(256) void k_prep(const float* __restrict__ feats,
                                              const float* __restrict__ lt, const int* __restrict__ layerp,
                                              const float* __restrict__ Wt2f,
                                              u16* __restrict__ xb, u16* __restrict__ wt_bf,
                                              u16* __restrict__ tok_bf, u16* __restrict__ A2,
                                              float* __restrict__ outp) {
  int tid = blockIdx.x * 256 + threadIdx.x;   // 524288 total
  int L = *layerp;
  const float4* in4 = (const float4*)(feats + 32768);
  ushort4v* xb4 = (ushort4v*)xb;
  #pragma unroll
  for (int rep = 0; rep < 16; ++rep) {
    int j = tid + rep * 524288;
    float4 v = in4[j];
    ushort4v o;
    o[0] = f2bf(v.x); o[1] = f2bf(v.y); o[2] = f2bf(v.z); o[3] = f2bf(v.w);
    xb4[j] = o;
  }
  ((ushort8*)A2)[tid] = (ushort8){0,0,0,0,0,0,0,0};
  if (tid < 262144) {
    float4 v = ((const float4*)Wt2f)[tid];
    ushort4v o;
    o[0] = f2bf(v.x); o[1] = f2bf(v.y); o[2] = f2bf(v.z); o[3] = f2bf(v.w);
    ((ushort4v*)wt_bf)[tid] = o;
  }
  if (tid < 32768) {
    outp[tid] = feats[tid];
    int m = tid >> 8;
    ushort4v o = (ushort4v){0,0,0,0};
    if (m < 99) {
      float4 v = *(const float4*)(lt + (size_t)L * 102400 + (size_t)(m + 1) * 1024 + (tid & 255) * 4);
      o[0] = f2bf(v.x); o[1] = f2bf(v.y); o[2] = f2bf(v.z); o[3] = f2bf(v.w);
    }
    ((ushort4v*)tok_bf)[tid] = o;
  }
}

// ---------------- masked-DCT adjoint of one 1024-row (32x32 image) ----------------
__device__ void mdct_row(const float* __restrict__ row, u16* __restrict__ dst, float* sm, int t) {
  float* Ms = sm; float* T1 = sm + 1056; float* Dsh = sm + 2112;
  for (int i = t; i < 1024; i += 256) {
    int r = i >> 5, c = i & 31;
    Dsh[r * 33 + c] = dct_val(r, c);
    Ms[r * 33 + c] = row[i] * im_val(r, c);
  }
  __syncthreads();
  int k = t >> 3, l0 = (t & 7) * 4;
  float a0 = 0, a1 = 0, a2 = 0, a3 = 0;
  #pragma unroll 8
  for (int i = 0; i < 32; ++i) {
    float d = Dsh[i * 33 + k];
    const float* mr = &Ms[i * 33 + l0];
    a0 += d * mr[0]; a1 += d * mr[1]; a2 += d * mr[2]; a3 += d * mr[3];
  }
  T1[k * 33 + l0 + 0] = a0; T1[k * 33 + l0 + 1] = a1;
  T1[k * 33 + l0 + 2] = a2; T1[k * 33 + l0 + 3] = a3;
  __syncthreads();
  float b0 = 0, b1 = 0, b2 = 0, b3 = 0;
  #pragma unroll 8
  for (int j = 0; j < 32; ++j) {
    float u = T1[k * 33 + j];
    b0 += u * Dsh[j * 33 + l0 + 0];
    b1 += u * Dsh[j * 33 + l0 + 1];
    b2 += u * Dsh[j * 33 + l0 + 2];
    b3 += u * Dsh[j * 33 + l0 + 3];
  }
  ushort4v o;
  o[0] = f2bf(b0); o[1] = f2bf(b1); o[2] = f2bf(b2); o[3] = f2bf(b3);
  *(ushort4v*)(dst + k * 32 + l0) = o;
}

// ---------------- setupA: weff (256) + beff (1) + tok2 mdct (128) ----------------
__global__ __launch_bounds__(256) void k_setupA(const float* __restrict__ Wdf, const float* __restrict__ bdf,
                                                const float* __restrict__ lt, const int* __restrict__ layerp,
                                                float* __restrict__ weff_f, u16* __restrict__ weff_bf,
                                                float* __restrict__ beff, u16* __restrict__ tok2) {
  __shared__ __align__(16) float sm[14784];
  int bid = blockIdx.x, t = threadIdx.x;
  if (bid < 256) {
    float* In = sm; float* Uc = sm + 4224; float* Us = sm + 8448;
    float* Csh = sm + 12672; float* Ssh = sm + 13728;
    int c0 = bid * 4;
    for (int i = t; i < 1024; i += 256) {
      int r = i >> 5, c = i & 31;
      float ang = (float)((r * c) & 31) * (PI_F / 16.0f);
      Csh[r * 33 + c] = cosf(ang); Ssh[r * 33 + c] = sinf(ang);
    }
    { int cc = t & 3, v0 = t >> 2;
      for (int v = v0; v < 1024; v += 64)
        In[cc * 1056 + (v >> 5) * 33 + (v & 31)] = Wdf[(size_t)v * 1024 + c0 + cc]; }
    __syncthreads();
    int cc = t >> 6, L2 = t & 63, p = L2 & 31, h = L2 >> 5;
    for (int j = h * 16; j < h * 16 + 16; ++j) {
      float ac = 0, as = 0;
      #pragma unroll 8
      for (int i = 0; i < 32; ++i) {
        float m = In[cc * 1056 + i * 33 + j];
        ac += Csh[p * 33 + i] * m;
        as += Ssh[p * 33 + i] * m;
      }
      Uc[cc * 1056 + p * 33 + j] = ac;
      Us[cc * 1056 + p * 33 + j] = as;
    }
    __syncthreads();
    for (int q = h * 16; q < h * 16 + 16; ++q) {
      float acc = 0;
      #pragma unroll 8
      for (int j = 0; j < 32; ++j)
        acc += Uc[cc * 1056 + p * 33 + j] * Csh[q * 33 + j] -
               Us[cc * 1056 + p * 33 + j] * Ssh[q * 33 + j];
      float val = acc * 0.03125f;
      size_t idx = (size_t)(p * 32 + q) * 1024 + c0 + cc;
      weff_f[idx] = val;
      weff_bf[idx] = f2bf(val);
    }
  } else if (bid == 256) {
    float* Bsh = sm; float* Uc = sm + 1056; float* Us = sm + 2112;
    float* Csh = sm + 3168; float* Ssh = sm + 4224;
    for (int i = t; i < 1024; i += 256) {
      int r = i >> 5, c = i & 31;
      float ang = (float)((r * c) & 31) * (PI_F / 16.0f);
      Csh[r * 33 + c] = cosf(ang); Ssh[r * 33 + c] = sinf(ang);
      Bsh[r * 33 + c] = bdf[i];
    }
    __syncthreads();
    for (int idx = t; idx < 1024; idx += 256) {
      int p = idx >> 5, j = idx & 31;
      float ac = 0, as = 0;
      #pragma unroll 8
      for (int i = 0; i < 32; ++i) {
        float m = Bsh[i * 33 + j];
        ac += Csh[p * 33 + i] * m;
        as += Ssh[p * 33 + i] * m;
      }
      Uc[p * 33 + j] = ac; Us[p * 33 + j] = as;
    }
    __syncthreads();
    for (int idx = t; idx < 1024; idx += 256) {
      int p = idx >> 5, q = idx & 31;
      float acc = 0;
      #pragma unroll 8
      for (int jj = 0; jj < 32; ++jj)
        acc += Uc[p * 33 + jj] * Csh[q * 33 + jj] - Us[p * 33 + jj] * Ssh[q * 33 + jj];
      beff[idx] = acc * 0.03125f;
    }
  } else {
    int p = bid - 257;   // 0..127, tok2 row (tokens[0..99], pad 100..127)
    if (p >= 100) {
      *(ushort4v*)(tok2 + (size_t)p * 1024 + t * 4) = (ushort4v){0,0,0,0};
      return;
    }
    mdct_row(lt + (size_t)(*layerp) * 102400 + (size_t)p * 1024, tok2 + (size_t)p * 1024, sm, t);
  }
}

// ---------------- 128x128 dbuf GEMM core (NT K-tiles of 32) ----------------
template <int NT>
__device__ __forceinline__ void gemm128_core(const u16* __restrict__ A, int lda,
                                             const u16* __restrict__ B, int ldb,
                                             int g0, int c0, u16* sA, u16* sB,
                                             f32x4 (&acc)[4][4], int wid, int lane) {
  int wr = wid >> 1, wc = wid & 1, cl = lane & 15, rg = lane >> 4;
  stage_tile(A, lda, g0, 0, sA, wid, lane);
  stage_tile(B, ldb, c0, 0, sB, wid, lane);
  __syncthreads();
  #pragma unroll 1
  for (int kt = 0; kt < NT; ++kt) {
    int cur = kt & 1;
    if (kt + 1 < NT) {
      stage_tile(A, lda, g0, (kt + 1) * 32, sA + (cur ^ 1) * 4096, wid, lane);
      stage_tile(B, ldb, c0, (kt + 1) * 32, sB + (cur ^ 1) * 4096, wid, lane);
    }
    const u16* pa = sA + cur * 4096;
    const u16* pb = sB + cur * 4096;
    bf16x8 af[4], bv[4];
    #pragma unroll
    for (int mf = 0; mf < 4; mf++)
      af[mf] = *(const bf16x8*)(pa + (wr * 64 + mf * 16 + cl) * 32 + rg * 8);
    #pragma unroll
    for (int nf = 0; nf < 4; nf++)
      bv[nf] = *(const bf16x8*)(pb + (wc * 64 + nf * 16 + cl) * 32 + rg * 8);
    #pragma unroll
    for (int mf = 0; mf < 4; mf++)
      #pragma unroll
      for (int nf = 0; nf < 4; nf++)
        acc[mf][nf] = __builtin_amdgcn_mfma_f32_16x16x32_bf16(af[mf], bv[nf], acc[mf][nf], 0, 0, 0);
    __syncthreads();
  }
}

// ---------------- setupB: w2 mdct (1024) + t2f GEMM (8) ----------------
__global__ __launch_bounds__(256) void k_setupB(const float* __restrict__ weff_f,
                                                const u16* __restrict__ tok_bf, const u16* __restrict__ wt_bf,
                                                const float* __restrict__ bt2f,
                                                u16* __restrict__ w2, u16* __restrict__ t2f) {
  __shared__ __align__(16) u16 smem[16384];
  int bid = blockIdx.x, t = threadIdx.x;
  if (bid < 1024) {
    mdct_row(weff_f + (size_t)bid * 1024, w2 + (size_t)bid * 1024, (float*)smem, t);
  } else {
    int bn = bid - 1024;
    int lane = t & 63, wid = t >> 6;
    int wr = wid >> 1, wc = wid & 1, cl = lane & 15, rg = lane >> 4;
    f32x4 acc[4][4];
    #pragma unroll
    for (int i = 0; i < 4; i++)
      #pragma unroll
      for (int j = 0; j < 4; j++) acc[i][j] = (f32x4){0.f,0.f,0.f,0.f};
    gemm128_core<32>(tok_bf, 1024, wt_bf, 1024, 0, bn * 128, smem, smem + 8192, acc, wid, lane);
    #pragma unroll
    for (int mf = 0; mf < 4; mf++)
      #pragma unroll
      for (int nf = 0; nf < 4; nf++) {
        int col = bn * 128 + wc * 64 + nf * 16 + cl;
        #pragma unroll
        for (int r = 0; r < 4; r++) {
          int row = wr * 64 + mf * 16 + rg * 4 + r;
          t2f[(size_t)row * 1024 + col] = (row < 99) ? f2bf(acc[mf][nf][r] + bt2f[col]) : (u16)0;
        }
      }
  }
}

// ---------------- setupC: Gt GEMM (8) + attn GEMM+softmax (256) ----------------
__global__ __launch_bounds__(256) void k_setupC(const u16* __restrict__ weff_bf, const u16* __restrict__ t2f,
                                                const u16* __restrict__ xb, const u16* __restrict__ tok2,
                                                u16* __restrict__ Gt, u16* __restrict__ A2) {
  __shared__ __align__(16) u16 smem[16384];
  int bid = blockIdx.x, t = threadIdx.x;
  int lane = t & 63, wid = t >> 6;
  if (bid < 8) {
    int wr = wid >> 1, wc = wid & 1, cl = lane & 15, rg = lane >> 4;
    f32x4 acc[4][4];
    #pragma unroll
    for (int i = 0; i < 4; i++)
      #pragma unroll
      for (int j = 0; j < 4; j++) acc[i][j] = (f32x4){0.f,0.f,0.f,0.f};
    gemm128_core<32>(weff_bf, 1024, t2f, 1024, bid * 128, 0, smem, smem + 8192, acc, wid, lane);
    #pragma unroll
    for (int mf = 0; mf < 4; mf++)
      #pragma unroll
      for (int nf = 0; nf < 4; nf++) {
        int col = wc * 64 + nf * 16 + cl;
        #pragma unroll
        for (int r = 0; r < 4; r++) {
          int row = bid * 128 + wr * 64 + mf * 16 + rg * 4 + r;
          Gt[(size_t)row * 128 + col] = f2bf(acc[mf][nf][r]);
        }
      }
  } else {
    int g0 = (bid - 8) * 128;
    int cl = lane & 15, rg = lane >> 4;
    u16* sA = smem; u16* sB = smem + 8192;
    f32x4 acc[2][7];
    #pragma unroll
    for (int i = 0; i < 2; i++)
      #pragma unroll
      for (int j = 0; j < 7; j++) acc[i][j] = (f32x4){0.f,0.f,0.f,0.f};
    stage_tile(xb, 1024, g0, 0, sA, wid, lane);
    stage_tile(tok2, 1024, 0, 0, sB, wid, lane);
    __syncthreads();
    #pragma unroll 1
    for (int kt = 0; kt < 32; ++kt) {
      int cur = kt & 1;
      if (kt + 1 < 32) {
        stage_tile(xb, 1024, g0, (kt + 1) * 32, sA + (cur ^ 1) * 4096, wid, lane);
        stage_tile(tok2, 1024, 0, (kt + 1) * 32, sB + (cur ^ 1) * 4096, wid, lane);
      }
      const u16* pa = sA + cur * 4096;
      const u16* pb = sB + cur * 4096;
      bf16x8 a0 = *(const bf16x8*)(pa + (wid * 32 + cl) * 32 + rg * 8);
      bf16x8 a1 = *(const bf16x8*)(pa + (wid * 32 + 16 + cl) * 32 + rg * 8);
      #pragma unroll
      for (int nf = 0; nf < 7; nf++) {
        bf16x8 bv = *(const bf16x8*)(pb + (nf * 16 + cl) * 32 + rg * 8);
        acc[0][nf] = __builtin_amdgcn_mfma_f32_16x16x32_bf16(a0, bv, acc[0][nf], 0, 0, 0);
        acc[1][nf] = __builtin_amdgcn_mfma_f32_16x16x32_bf16(a1, bv, acc[1][nf], 0, 0, 0);
      }
      __syncthreads();
    }
    #pragma unroll
    for (int mf = 0; mf < 2; mf++) {
      #pragma unroll
      for (int r = 0; r < 4; r++) {
        int grow = g0 + wid * 32 + mf * 16 + rg * 4 + r;
        float v[7];
        float mx = -1e30f;
        #pragma unroll
        for (int nf = 0; nf < 7; nf++) {
          int m = nf * 16 + cl;
          v[nf] = acc[mf][nf][r] * 0.03125f;
          if (m < 100) mx = fmaxf(mx, v[nf]);
        }
        #pragma unroll
        for (int d = 1; d < 16; d <<= 1) mx = fmaxf(mx, __shfl_xor(mx, d));
        float s = 0;
        #pragma unroll
        for (int nf = 0; nf < 7; nf++) {
          int m = nf * 16 + cl;
          float e = (m < 100) ? __expf(v[nf] - mx) : 0.0f;
          v[nf] = e; s += e;
        }
        #pragma unroll
        for (int d = 1; d < 16; d <<= 1) s += __shfl_xor(s, d);
        float inv = 1.0f / s;
        #pragma unroll
        for (int nf = 0; nf < 7; nf++) {
          int m = nf * 16 + cl;
          if (m >= 1 && m < 100) A2[(size_t)grow * 128 + (m - 1)] = f2bf(v[nf] * inv);
        }
      }
    }
  }
}

// ---------------- main fused GEMM: out = x + clip([xb|A2]@[w2|Gt]^T + beff)*scale --------
__global__ __launch_bounds__(256) void k_main(const u16* __restrict__ xb, const u16* __restrict__ w2,
                                              const u16* __restrict__ a2, const u16* __restrict__ gt,
                                              const float* __restrict__ beff, const float* __restrict__ feats,
                                              const float* __restrict__ scalep, float* __restrict__ outf) {
  __shared__ __align__(16) u16 smem[16384];
  u16* sA = smem; u16* sB = smem + 8192;
  int t = threadIdx.x, lane = t & 63, wid = t >> 6;
  int bid = blockIdx.x;
  int xcd = bid & 7, local = bid >> 3;
  int super = local >> 5, within = local & 31;
  int bm = xcd * 32 + super * 4 + (within & 3);
  int bn = within >> 2;
  int g0 = bm * 128, c0 = bn * 128;
  int wr = wid >> 1, wc = wid & 1;
  int cl = lane & 15, rg = lane >> 4;
  f32x4 acc[4][4];
  #pragma unroll
  for (int i = 0; i < 4; i++)
    #pragma unroll
    for (int j = 0; j < 4; j++) acc[i][j] = (f32x4){0.f,0.f,0.f,0.f};

  auto stage = [&](int kt, int b) {
    if (kt < 32) {
      stage_tile(xb, 1024, g0, kt * 32, sA + b * 4096, wid, lane);
      stage_tile(w2, 1024, c0, kt * 32, sB + b * 4096, wid, lane);
    } else {
      int k0 = (kt - 32) * 32;
      stage_tile(a2, 128, g0, k0, sA + b * 4096, wid, lane);
      stage_tile(gt, 128, c0, k0, sB + b * 4096, wid, lane);
    }
  };

  stage(0, 0);
  __syncthreads();
  #pragma unroll 1
  for (int kt = 0; kt < 36; ++kt) {
    int cur = kt & 1;
    if (kt + 1 < 36) stage(kt + 1, cur ^ 1);
    const u16* pa = sA + cur * 4096;
    const u16* pb = sB + cur * 4096;
    bf16x8 af[4], bv[4];
    #pragma unroll
    for (int mf = 0; mf < 4; mf++)
      af[mf] = *(const bf16x8*)(pa + (wr * 64 + mf * 16 + cl) * 32 + rg * 8);
    #pragma unroll
    for (int nf = 0; nf < 4; nf++)
      bv[nf] = *(const bf16x8*)(pb + (wc * 64 + nf * 16 + cl) * 32 + rg * 8);
    #pragma unroll
    for (int mf = 0; mf < 4; mf++)
      #pragma unroll
      for (int nf = 0; nf < 4; nf++)
        acc[mf][nf] = __builtin_amdgcn_mfma_f32_16x16x32_bf16(af[mf], bv[nf], acc[mf][nf], 0, 0, 0);
    __syncthreads();
  }

  float sc = *scalep;
  #pragma unroll
  for (int mf = 0; mf < 4; mf++) {
    #pragma unroll
    for (int nf = 0; nf < 4; nf++) {
      int col = c0 + wc * 64 + nf * 16 + cl;
      #pragma unroll
      for (int r = 0; r < 4; r++) {
        int row = g0 + wr * 64 + mf * 16 + rg * 4 + r;
        size_t idx = (size_t)row * 1024 + col;
        float val = acc[mf][nf][r] + beff[col];
        float rr = fminf(fmaxf(val, 0.f), 255.f);
        outf[32768 + idx] = feats[32768 + idx] + rr * sc;
      }
    }
  }
}

extern "C" void kernel_launch(void* const* d_in, const int* in_sizes, int n_in,
                              void* d_out, int out_size, void* d_ws, size_t ws_size,
                              hipStream_t stream) {
  const float* feats  = (const float*)d_in[0];
  const int*   layerp = (const int*)d_in[1];
  const float* lt     = (const float*)d_in[2];
  const float* scalep = (const float*)d_in[3];
  const float* Wt2f   = (const float*)d_in[4];
  const float* bt2f   = (const float*)d_in[5];
  const float* Wdf    = (const float*)d_in[6];
  const float* bdf    = (const float*)d_in[7];
  float* outp = (float*)d_out;

  char* ws = (char*)d_ws;
  float* beff   = (float*)(ws + 0);           // 4KB
  float* weff_f = (float*)(ws + 65536);       // 4MB
  u16* weff_bf = (u16*)(ws + 4259840);        // 2MB
  u16* w2      = (u16*)(ws + 6356992);        // 2MB
  u16* tok_bf  = (u16*)(ws + 8454144);        // 256KB (tokens[1:] padded to 128)
  u16* wt_bf   = (u16*)(ws + 8716288);        // 2MB
  u16* tok2    = (u16*)(ws + 10813440);       // 256KB
  u16* t2f     = (u16*)(ws + 11075584);       // 256KB
  u16* Gt      = (u16*)(ws + 11337728);       // 256KB (1024x128)
  u16* A2      = (u16*)(ws + 11599872);       // 8MB (32768x128)
  u16* xb      = (u16*)(ws + 19988480);       // 64MB (32768x1024)

  k_prep<<<2048, 256, 0, stream>>>(feats, lt, layerp, Wt2f, xb, wt_bf, tok_bf, A2, outp);
  k_setupA<<<385, 256, 0, stream>>>(Wdf, bdf, lt, layerp, weff_f, weff_bf, beff, tok2);
  k_setupB<<<1032, 256, 0, stream>>>(weff_f, tok_bf, wt_bf, bt2f, w2, t2f);
  k_setupC<<<264, 256, 0, stream>>>(weff_bf, t2f, xb, tok2, Gt, A2);
  k_main<<<2048, 256, 0, stream>>>(xb, w2, A2, Gt, beff, feats, scalep, outp);
}

// Round 5
// 246.785 us; speedup vs baseline: 4.8843x; 1.0303x over previous
//
#include <hip/hip_runtime.h>

typedef unsigned short u16;
typedef u16 ushort8 __attribute__((ext_vector_type(8)));
typedef u16 ushort4v __attribute__((ext_vector_type(4)));
typedef __bf16 bf16x8 __attribute__((ext_vector_type(8)));
typedef float f32x4 __attribute__((ext_vector_type(4)));

#define PI_F 3.14159265358979323846f

__device__ __forceinline__ u16 f2bf(float f) {
  union { float f; unsigned int u; } v; v.f = f;
  unsigned int r = v.u + 0x7fffu + ((v.u >> 16) & 1u);
  return (u16)(r >> 16);
}
__device__ __forceinline__ float bf2f(u16 u) {
  union { unsigned int u; float f; } v; v.u = ((unsigned int)u) << 16;
  return v.f;
}

// async global->LDS, 16B per lane; LDS dest = wave-uniform base + lane*16
__device__ __forceinline__ void gload16(const u16* g, u16* l) {
  __builtin_amdgcn_global_load_lds((const __attribute__((address_space(1))) void*)g,
                                   (__attribute__((address_space(3))) void*)l, 16, 0, 0);
}

// stage a 128x32 bf16 tile into linear LDS [128][32]  (2 gload16 per wave = 2 vmcnt ops)
__device__ __forceinline__ void stage_tile(const u16* __restrict__ G, int ld, int row0, int k0,
                                           u16* lds, int wid, int lane) {
  int seg = wid * 32;
  const u16* gp = G + (size_t)(row0 + seg + (lane >> 2)) * ld + k0 + (lane & 3) * 8;
  gload16(gp, lds + seg * 32);
  gload16(gp + (size_t)16 * ld, lds + (seg + 16) * 32);
}

#define WAIT_VM(N) asm volatile("s_waitcnt vmcnt(" #N ")" ::: "memory")
#define RAW_BARRIER() asm volatile("s_barrier" ::: "memory")

// local 32x32 tables
__device__ __forceinline__ float im_val(int r, int c) {
  float xy = (float)(r > c ? r : c);
  float m = (xy <= 3.0f) ? (1.0f - xy * (0.95f / 3.0f))
           : ((xy <= 22.0f) ? 0.01f : ((xy - 22.0f) * 0.03f));
  return 1.0f - m;
}
__device__ __forceinline__ float dct_val(int r, int c) {
  int a = ((2 * c + 1) * r) & 127;
  float s = (r == 0) ? 0.17677669529663687f : 0.25f;
  return cosf((float)a * (PI_F / 64.0f)) * s;
}

// ---------------- prep: xb, wt_bf, tok_bf, zero A2, cls copy ----------------
__global__ __launch_bounds__(256) void k_prep(const float* __restrict__ feats,
                                              const float* __restrict__ lt, const int* __restrict__ layerp,
                                              const float* __restrict__ Wt2f,
                                              u16* __restrict__ xb, u16* __restrict__ wt_bf,
                                              u16* __restrict__ tok_bf, u16* __restrict__ A2,
                                              float* __restrict__ outp) {
  int tid = blockIdx.x * 256 + threadIdx.x;   // 524288 total
  int L = *layerp;
  const float4* in4 = (const float4*)(feats + 32768);
  ushort4v* xb4 = (ushort4v*)xb;
  #pragma unroll
  for (int rep = 0; rep < 16; ++rep) {
    int j = tid + rep * 524288;
    float4 v = in4[j];
    ushort4v o;
    o[0] = f2bf(v.x); o[1] = f2bf(v.y); o[2] = f2bf(v.z); o[3] = f2bf(v.w);
    xb4[j] = o;
  }
  ((ushort8*)A2)[tid] = (ushort8){0,0,0,0,0,0,0,0};
  if (tid < 262144) {
    float4 v = ((const float4*)Wt2f)[tid];
    ushort4v o;
    o[0] = f2bf(v.x); o[1] = f2bf(v.y); o[2] = f2bf(v.z); o[3] = f2bf(v.w);
    ((ushort4v*)wt_bf)[tid] = o;
  }
  if (tid < 32768) {
    outp[tid] = feats[tid];
    int m = tid >> 8;
    ushort4v o = (ushort4v){0,0,0,0};
    if (m < 99) {
      float4 v = *(const float4*)(lt + (size_t)L * 102400 + (size_t)(m + 1) * 1024 + (tid & 255) * 4);
      o[0] = f2bf(v.x); o[1] = f2bf(v.y); o[2] = f2bf(v.z); o[3] = f2bf(v.w);
    }
    ((ushort4v*)tok_bf)[tid] = o;
  }
}

// ---------------- masked-DCT adjoint of one 1024-row (32x32 image) ----------------
__device__ void mdct_row(const float* __restrict__ row, u16* __restrict__ dst, float* sm, int t) {
  float* Ms = sm; float* T1 = sm + 1056; float* Dsh = sm + 2112;
  for (int i = t; i < 1024; i += 256) {
    int r = i >> 5, c = i & 31;
    Dsh[r * 33 + c] = dct_val(r, c);
    Ms[r * 33 + c] = row[i] * im_val(r, c);
  }
  __syncthreads();
  int k = t >> 3, l0 = (t & 7) * 4;
  float a0 = 0, a1 = 0, a2 = 0, a3 = 0;
  #pragma unroll 8
  for (int i = 0; i < 32; ++i) {
    float d = Dsh[i * 33 + k];
    const float* mr = &Ms[i * 33 + l0];
    a0 += d * mr[0]; a1 += d * mr[1]; a2 += d * mr[2]; a3 += d * mr[3];
  }
  T1[k * 33 + l0 + 0] = a0; T1[k * 33 + l0 + 1] = a1;
  T1[k * 33 + l0 + 2] = a2; T1[k * 33 + l0 + 3] = a3;
  __syncthreads();
  float b0 = 0, b1 = 0, b2 = 0, b3 = 0;
  #pragma unroll 8
  for (int j = 0; j < 32; ++j) {
    float u = T1[k * 33 + j];
    b0 += u * Dsh[j * 33 + l0 + 0];
    b1 += u * Dsh[j * 33 + l0 + 1];
    b2 += u * Dsh[j * 33 + l0 + 2];
    b3 += u * Dsh[j * 33 + l0 + 3];
  }
  ushort4v o;
  o[0] = f2bf(b0); o[1] = f2bf(b1); o[2] = f2bf(b2); o[3] = f2bf(b3);
  *(ushort4v*)(dst + k * 32 + l0) = o;
}

// ---------------- setupA: weff (256) + beff (1) + tok2 mdct (128) ----------------
__global__ __launch_bounds__(256) void k_setupA(const float* __restrict__ Wdf, const float* __restrict__ bdf,
                                                const float* __restrict__ lt, const int* __restrict__ layerp,
                                                float* __restrict__ weff_f, u16* __restrict__ weff_bf,
                                                float* __restrict__ beff, u16* __restrict__ tok2) {
  __shared__ __align__(16) float sm[14784];
  int bid = blockIdx.x, t = threadIdx.x;
  if (bid < 256) {
    float* In = sm; float* Uc = sm + 4224; float* Us = sm + 8448;
    float* Csh = sm + 12672; float* Ssh = sm + 13728;
    int c0 = bid * 4;
    for (int i = t; i < 1024; i += 256) {
      int r = i >> 5, c = i & 31;
      float ang = (float)((r * c) & 31) * (PI_F / 16.0f);
      Csh[r * 33 + c] = cosf(ang); Ssh[r * 33 + c] = sinf(ang);
    }
    { int cc = t & 3, v0 = t >> 2;
      for (int v = v0; v < 1024; v += 64)
        In[cc * 1056 + (v >> 5) * 33 + (v & 31)] = Wdf[(size_t)v * 1024 + c0 + cc]; }
    __syncthreads();
    int cc = t >> 6, L2 = t & 63, p = L2 & 31, h = L2 >> 5;
    for (int j = h * 16; j < h * 16 + 16; ++j) {
      float ac = 0, as = 0;
      #pragma unroll 8
      for (int i = 0; i < 32; ++i) {
        float m = In[cc * 1056 + i * 33 + j];
        ac += Csh[p * 33 + i] * m;
        as += Ssh[p * 33 + i] * m;
      }
      Uc[cc * 1056 + p * 33 + j] = ac;
      Us[cc * 1056 + p * 33 + j] = as;
    }
    __syncthreads();
    for (int q = h * 16; q < h * 16 + 16; ++q) {
      float acc = 0;
      #pragma unroll 8
      for (int j = 0; j < 32; ++j)
        acc += Uc[cc * 1056 + p * 33 + j] * Csh[q * 33 + j] -
               Us[cc * 1056 + p * 33 + j] * Ssh[q * 33 + j];
      float val = acc * 0.03125f;
      size_t idx = (size_t)(p * 32 + q) * 1024 + c0 + cc;
      weff_f[idx] = val;
      weff_bf[idx] = f2bf(val);
    }
  } else if (bid == 256) {
    float* Bsh = sm; float* Uc = sm + 1056; float* Us = sm + 2112;
    float* Csh = sm + 3168; float* Ssh = sm + 4224;
    for (int i = t; i < 1024; i += 256) {
      int r = i >> 5, c = i & 31;
      float ang = (float)((r * c) & 31) * (PI_F / 16.0f);
      Csh[r * 33 + c] = cosf(ang); Ssh[r * 33 + c] = sinf(ang);
      Bsh[r * 33 + c] = bdf[i];
    }
    __syncthreads();
    for (int idx = t; idx < 1024; idx += 256) {
      int p = idx >> 5, j = idx & 31;
      float ac = 0, as = 0;
      #pragma unroll 8
      for (int i = 0; i < 32; ++i) {
        float m = Bsh[i * 33 + j];
        ac += Csh[p * 33 + i] * m;
        as += Ssh[p * 33 + i] * m;
      }
      Uc[p * 33 + j] = ac; Us[p * 33 + j] = as;
    }
    __syncthreads();
    for (int idx = t; idx < 1024; idx += 256) {
      int p = idx >> 5, q = idx & 31;
      float acc = 0;
      #pragma unroll 8
      for (int jj = 0; jj < 32; ++jj)
        acc += Uc[p * 33 + jj] * Csh[q * 33 + jj] - Us[p * 33 + jj] * Ssh[q * 33 + jj];
      beff[idx] = acc * 0.03125f;
    }
  } else {
    int p = bid - 257;   // 0..127, tok2 row (tokens[0..99], pad 100..127)
    if (p >= 100) {
      *(ushort4v*)(tok2 + (size_t)p * 1024 + t * 4) = (ushort4v){0,0,0,0};
      return;
    }
    mdct_row(lt + (size_t)(*layerp) * 102400 + (size_t)p * 1024, tok2 + (size_t)p * 1024, sm, t);
  }
}

// ---------------- 128x128 ring-buffer GEMM core (NT K-tiles of 32), counted vmcnt ------
// smem layout: A slots at 0,4096,8192 ; B slots at 12288,16384,20480 (u16 units)
template <int NT>
__device__ __forceinline__ void gemm128_core(const u16* __restrict__ A, int lda,
                                             const u16* __restrict__ B, int ldb,
                                             int g0, int c0, u16* smem,
                                             f32x4 (&acc)[4][4], int wid, int lane) {
  int wr = wid >> 1, wc = wid & 1, cl = lane & 15, rg = lane >> 4;
  stage_tile(A, lda, g0, 0, smem, wid, lane);
  stage_tile(B, ldb, c0, 0, smem + 12288, wid, lane);
  stage_tile(A, lda, g0, 32, smem + 4096, wid, lane);
  stage_tile(B, ldb, c0, 32, smem + 16384, wid, lane);
  int cur = 0;
  #pragma unroll 1
  for (int kt = 0; kt < NT; ++kt) {
    if (kt == NT - 1) { WAIT_VM(0); } else { WAIT_VM(4); }
    RAW_BARRIER();
    if (kt + 2 < NT) {
      int slot = (cur == 0) ? 2 : cur - 1;
      stage_tile(A, lda, g0, (kt + 2) * 32, smem + slot * 4096, wid, lane);
      stage_tile(B, ldb, c0, (kt + 2) * 32, smem + 12288 + slot * 4096, wid, lane);
    }
    const u16* pa = smem + cur * 4096;
    const u16* pb = smem + 12288 + cur * 4096;
    bf16x8 af[4], bv[4];
    #pragma unroll
    for (int mf = 0; mf < 4; mf++)
      af[mf] = *(const bf16x8*)(pa + (wr * 64 + mf * 16 + cl) * 32 + rg * 8);
    #pragma unroll
    for (int nf = 0; nf < 4; nf++)
      bv[nf] = *(const bf16x8*)(pb + (wc * 64 + nf * 16 + cl) * 32 + rg * 8);
    #pragma unroll
    for (int mf = 0; mf < 4; mf++)
      #pragma unroll
      for (int nf = 0; nf < 4; nf++)
        acc[mf][nf] = __builtin_amdgcn_mfma_f32_16x16x32_bf16(af[mf], bv[nf], acc[mf][nf], 0, 0, 0);
    cur = (cur == 2) ? 0 : cur + 1;
  }
}

// ---------------- setupB: w2 mdct (1024) + t2f GEMM (8) ----------------
__global__ __launch_bounds__(256) void k_setupB(const float* __restrict__ weff_f,
                                                const u16* __restrict__ tok_bf, const u16* __restrict__ wt_bf,
                                                const float* __restrict__ bt2f,
                                                u16* __restrict__ w2, u16* __restrict__ t2f) {
  __shared__ __align__(16) u16 smem[24576];
  int bid = blockIdx.x, t = threadIdx.x;
  if (bid < 1024) {
    mdct_row(weff_f + (size_t)bid * 1024, w2 + (size_t)bid * 1024, (float*)smem, t);
  } else {
    int bn = bid - 1024;
    int lane = t & 63, wid = t >> 6;
    int wr = wid >> 1, wc = wid & 1, cl = lane & 15, rg = lane >> 4;
    f32x4 acc[4][4];
    #pragma unroll
    for (int i = 0; i < 4; i++)
      #pragma unroll
      for (int j = 0; j < 4; j++) acc[i][j] = (f32x4){0.f,0.f,0.f,0.f};
    gemm128_core<32>(tok_bf, 1024, wt_bf, 1024, 0, bn * 128, smem, acc, wid, lane);
    #pragma unroll
    for (int mf = 0; mf < 4; mf++)
      #pragma unroll
      for (int nf = 0; nf < 4; nf++) {
        int col = bn * 128 + wc * 64 + nf * 16 + cl;
        #pragma unroll
        for (int r = 0; r < 4; r++) {
          int row = wr * 64 + mf * 16 + rg * 4 + r;
          t2f[(size_t)row * 1024 + col] = (row < 99) ? f2bf(acc[mf][nf][r] + bt2f[col]) : (u16)0;
        }
      }
  }
}

// ---------------- setupC: Gt GEMM (8) + attn GEMM+softmax (256) ----------------
__global__ __launch_bounds__(256) void k_setupC(const u16* __restrict__ weff_bf, const u16* __restrict__ t2f,
                                                const u16* __restrict__ xb, const u16* __restrict__ tok2,
                                                u16* __restrict__ Gt, u16* __restrict__ A2) {
  __shared__ __align__(16) u16 smem[24576];
  int bid = blockIdx.x, t = threadIdx.x;
  int lane = t & 63, wid = t >> 6;
  if (bid < 8) {
    int wr = wid >> 1, wc = wid & 1, cl = lane & 15, rg = lane >> 4;
    f32x4 acc[4][4];
    #pragma unroll
    for (int i = 0; i < 4; i++)
      #pragma unroll
      for (int j = 0; j < 4; j++) acc[i][j] = (f32x4){0.f,0.f,0.f,0.f};
    gemm128_core<32>(weff_bf, 1024, t2f, 1024, bid * 128, 0, smem, acc, wid, lane);
    #pragma unroll
    for (int mf = 0; mf < 4; mf++)
      #pragma unroll
      for (int nf = 0; nf < 4; nf++) {
        int col = wc * 64 + nf * 16 + cl;
        #pragma unroll
        for (int r = 0; r < 4; r++) {
          int row = bid * 128 + wr * 64 + mf * 16 + rg * 4 + r;
          Gt[(size_t)row * 128 + col] = f2bf(acc[mf][nf][r]);
        }
      }
  } else {
    int g0 = (bid - 8) * 128;
    int cl = lane & 15, rg = lane >> 4;
    f32x4 acc[2][7];
    #pragma unroll
    for (int i = 0; i < 2; i++)
      #pragma unroll
      for (int j = 0; j < 7; j++) acc[i][j] = (f32x4){0.f,0.f,0.f,0.f};
    stage_tile(xb, 1024, g0, 0, smem, wid, lane);
    stage_tile(tok2, 1024, 0, 0, smem + 12288, wid, lane);
    stage_tile(xb, 1024, g0, 32, smem + 4096, wid, lane);
    stage_tile(tok2, 1024, 0, 32, smem + 16384, wid, lane);
    int cur = 0;
    #pragma unroll 1
    for (int kt = 0; kt < 32; ++kt) {
      if (kt == 31) { WAIT_VM(0); } else { WAIT_VM(4); }
      RAW_BARRIER();
      if (kt + 2 < 32) {
        int slot = (cur == 0) ? 2 : cur - 1;
        stage_tile(xb, 1024, g0, (kt + 2) * 32, smem + slot * 4096, wid, lane);
        stage_tile(tok2, 1024, 0, (kt + 2) * 32, smem + 12288 + slot * 4096, wid, lane);
      }
      const u16* pa = smem + cur * 4096;
      const u16* pb = smem + 12288 + cur * 4096;
      bf16x8 a0 = *(const bf16x8*)(pa + (wid * 32 + cl) * 32 + rg * 8);
      bf16x8 a1 = *(const bf16x8*)(pa + (wid * 32 + 16 + cl) * 32 + rg * 8);
      #pragma unroll
      for (int nf = 0; nf < 7; nf++) {
        bf16x8 bv = *(const bf16x8*)(pb + (nf * 16 + cl) * 32 + rg * 8);
        acc[0][nf] = __builtin_amdgcn_mfma_f32_16x16x32_bf16(a0, bv, acc[0][nf], 0, 0, 0);
        acc[1][nf] = __builtin_amdgcn_mfma_f32_16x16x32_bf16(a1, bv, acc[1][nf], 0, 0, 0);
      }
      cur = (cur == 2) ? 0 : cur + 1;
    }
    #pragma unroll
    for (int mf = 0; mf < 2; mf++) {
      #pragma unroll
      for (int r = 0; r < 4; r++) {
        int grow = g0 + wid * 32 + mf * 16 + rg * 4 + r;
        float v[7];
        float mx = -1e30f;
        #pragma unroll
        for (int nf = 0; nf < 7; nf++) {
          int m = nf * 16 + cl;
          v[nf] = acc[mf][nf][r] * 0.03125f;
          if (m < 100) mx = fmaxf(mx, v[nf]);
        }
        #pragma unroll
        for (int d = 1; d < 16; d <<= 1) mx = fmaxf(mx, __shfl_xor(mx, d));
        float s = 0;
        #pragma unroll
        for (int nf = 0; nf < 7; nf++) {
          int m = nf * 16 + cl;
          float e = (m < 100) ? __expf(v[nf] - mx) : 0.0f;
          v[nf] = e; s += e;
        }
        #pragma unroll
        for (int d = 1; d < 16; d <<= 1) s += __shfl_xor(s, d);
        float inv = 1.0f / s;
        #pragma unroll
        for (int nf = 0; nf < 7; nf++) {
          int m = nf * 16 + cl;
          if (m >= 1 && m < 100) A2[(size_t)grow * 128 + (m - 1)] = f2bf(v[nf] * inv);
        }
      }
    }
  }
}

// ---------------- main fused GEMM: out = x + clip([xb|A2]@[w2|Gt]^T + beff)*scale --------
__global__ __launch_bounds__(256) void k_main(const u16* __restrict__ xb, const u16* __restrict__ w2,
                                              const u16* __restrict__ a2, const u16* __restrict__ gt,
                                              const float* __restrict__ beff, const float* __restrict__ feats,
                                              const float* __restrict__ scalep, float* __restrict__ outf) {
  __shared__ __align__(16) u16 smem[24576];   // 48 KB: 3 A-slots + 3 B-slots
  int t = threadIdx.x, lane = t & 63, wid = t >> 6;
  int bid = blockIdx.x;
  int xcd = bid & 7, local = bid >> 3;
  int super = local >> 5, within = local & 31;
  int bm = xcd * 32 + super * 4 + (within & 3);
  int bn = within >> 2;
  int g0 = bm * 128, c0 = bn * 128;
  int wr = wid >> 1, wc = wid & 1;
  int cl = lane & 15, rg = lane >> 4;
  f32x4 acc[4][4];
  #pragma unroll
  for (int i = 0; i < 4; i++)
    #pragma unroll
    for (int j = 0; j < 4; j++) acc[i][j] = (f32x4){0.f,0.f,0.f,0.f};

  auto stage = [&](int kt, int slot) {
    u16* sa = smem + slot * 4096;
    u16* sb = smem + 12288 + slot * 4096;
    if (kt < 32) {
      stage_tile(xb, 1024, g0, kt * 32, sa, wid, lane);
      stage_tile(w2, 1024, c0, kt * 32, sb, wid, lane);
    } else {
      int k0 = (kt - 32) * 32;
      stage_tile(a2, 128, g0, k0, sa, wid, lane);
      stage_tile(gt, 128, c0, k0, sb, wid, lane);
    }
  };

  stage(0, 0);
  stage(1, 1);
  int cur = 0;
  #pragma unroll 1
  for (int kt = 0; kt < 36; ++kt) {
    if (kt == 35) { WAIT_VM(0); } else { WAIT_VM(4); }
    RAW_BARRIER();
    if (kt + 2 < 36) stage(kt + 2, (cur == 0) ? 2 : cur - 1);
    const u16* pa = smem + cur * 4096;
    const u16* pb = smem + 12288 + cur * 4096;
    bf16x8 af[4], bv[4];
    #pragma unroll
    for (int mf = 0; mf < 4; mf++)
      af[mf] = *(const bf16x8*)(pa + (wr * 64 + mf * 16 + cl) * 32 + rg * 8);
    #pragma unroll
    for (int nf = 0; nf < 4; nf++)
      bv[nf] = *(const bf16x8*)(pb + (wc * 64 + nf * 16 + cl) * 32 + rg * 8);
    #pragma unroll
    for (int mf = 0; mf < 4; mf++)
      #pragma unroll
      for (int nf = 0; nf < 4; nf++)
        acc[mf][nf] = __builtin_amdgcn_mfma_f32_16x16x32_bf16(af[mf], bv[nf], acc[mf][nf], 0, 0, 0);
    cur = (cur == 2) ? 0 : cur + 1;
  }

  float sc = *scalep;
  #pragma unroll
  for (int mf = 0; mf < 4; mf++) {
    #pragma unroll
    for (int nf = 0; nf < 4; nf++) {
      int col = c0 + wc * 64 + nf * 16 + cl;
      #pragma unroll
      for (int r = 0; r < 4; r++) {
        int row = g0 + wr * 64 + mf * 16 + rg * 4 + r;
        size_t idx = (size_t)row * 1024 + col;
        float val = acc[mf][nf][r] + beff[col];
        float rr = fminf(fmaxf(val, 0.f), 255.f);
        outf[32768 + idx] = feats[32768 + idx] + rr * sc;
      }
    }
  }
}

extern "C" void kernel_launch(void* const* d_in, const int* in_sizes, int n_in,
                              void* d_out, int out_size, void* d_ws, size_t ws_size,
                              hipStream_t stream) {
  const float* feats  = (const float*)d_in[0];
  const int*   layerp = (const int*)d_in[1];
  const float* lt     = (const float*)d_in[2];
  const float* scalep = (const float*)d_in[3];
  const float* Wt2f   = (const float*)d_in[4];
  const float* bt2f   = (const float*)d_in[5];
  const float* Wdf    = (const float*)d_in[6];
  const float* bdf    = (const float*)d_in[7];
  float* outp = (float*)d_out;

  char* ws = (char*)d_ws;
  float* beff   = (float*)(ws + 0);           // 4KB
  float* weff_f = (float*)(ws + 65536);       // 4MB
  u16* weff_bf = (u16*)(ws + 4259840);        // 2MB
  u16* w2      = (u16*)(ws + 6356992);        // 2MB
  u16* tok_bf  = (u16*)(ws + 8454144);        // 256KB (tokens[1:] padded to 128)
  u16* wt_bf   = (u16*)(ws + 8716288);        // 2MB
  u16* tok2    = (u16*)(ws + 10813440);       // 256KB
  u16* t2f     = (u16*)(ws + 11075584);       // 256KB
  u16* Gt      = (u16*)(ws + 11337728);       // 256KB (1024x128)
  u16* A2      = (u16*)(ws + 11599872);       // 8MB (32768x128)
  u16* xb      = (u16*)(ws + 19988480);       // 64MB (32768x1024)

  k_prep<<<2048, 256, 0, stream>>>(feats, lt, layerp, Wt2f, xb, wt_bf, tok_bf, A2, outp);
  k_setupA<<<385, 256, 0, stream>>>(Wdf, bdf, lt, layerp, weff_f, weff_bf, beff, tok2);
  k_setupB<<<1032, 256, 0, stream>>>(weff_f, tok_bf, wt_bf, bt2f, w2, t2f);
  k_setupC<<<264, 256, 0, stream>>>(weff_bf, t2f, xb, tok2, Gt, A2);
  k_main<<<2048, 256, 0, stream>>>(xb, w2, A2, Gt, beff, feats, scalep, outp);
}